// Round 2
// baseline (2201.839 us; speedup 1.0000x reference)
//
#include <hip/hip_runtime.h>
#include <math.h>

typedef _Float16 h8 __attribute__((ext_vector_type(8)));
typedef _Float16 h2 __attribute__((ext_vector_type(2)));
typedef float f32x4 __attribute__((ext_vector_type(4)));

__device__ __forceinline__ float clampf(float x, float lo, float hi) {
    return fminf(fmaxf(x, lo), hi);
}

__global__ void zero_ints(int* __restrict__ p, int n) {
    int i = blockIdx.x * 256 + threadIdx.x;
    if (i < n) p[i] = 0;
}

// fp16 B-frag repack for CIN=64 layers, c-split (H = c-half) permuted k' layout:
// per half: k' < 2048: rowi = k'>>8; ivd = (k'>>6)&3; c' = (k'>>1)&31; slot = k'&1;
//            iv = ivd*2+slot; orig (k,c) = (rowi*8+iv, H*32+c')  -> cw
// k' >= 2048: fw row c = H*32 + (k'-2048)
// Wh linear idx = (((H*4 + t)*65 + s)*512) + l*8 + j ; kp = s*32 + (l>>4)*8 + j
__global__ void repack_wh(const float* __restrict__ cw, const float* __restrict__ fw,
                          _Float16* __restrict__ Wh, int COUT) {
    int idx = blockIdx.x * 256 + threadIdx.x;
    int total = 2 * 4 * 65 * 512;
    if (idx >= total) return;
    int j = idx & 7;
    int l = (idx >> 3) & 63;
    int rest = idx >> 9;
    int s = rest % 65;
    int r2 = rest / 65;
    int t = r2 & 3;
    int H = r2 >> 2;
    int kp = s * 32 + (l >> 4) * 8 + j;
    int co = t * 16 + (l & 15);
    float v = 0.f;
    if (co < COUT) {
        if (kp < 2048) {
            int rowi = kp >> 8;
            int ivd = (kp >> 6) & 3;
            int cp = (kp >> 1) & 31;
            int slot = kp & 1;
            int iv = ivd * 2 + slot;
            int c = H * 32 + cp;
            v = cw[((rowi * 8 + iv) * 64 + c) * COUT + co];
        } else {
            int c = H * 32 + (kp - 2048);
            v = fw[c * COUT + co];
        }
    }
    Wh[idx] = (_Float16)v;
}

__global__ void edge_hist(const int* __restrict__ ei, const int* __restrict__ ej,
                          int* __restrict__ counts, int E) {
    int e = blockIdx.x * 256 + threadIdx.x;
    if (e >= E) return;
    int i = ei[e], j = ej[e];
    if (i != j) atomicAdd(&counts[i], 1);
}

__global__ __launch_bounds__(1024) void scan_kernel(const int* __restrict__ counts,
                                                    int* __restrict__ offs,
                                                    int* __restrict__ cursor, int N) {
    __shared__ int sums[1024];
    const int t = threadIdx.x;
    const int per = (N + 1023) / 1024;
    const int lo = t * per;
    const int hi = min(lo + per, N);
    int s = 0;
    for (int i = lo; i < hi; ++i) s += counts[i];
    sums[t] = s;
    __syncthreads();
    for (int d = 1; d < 1024; d <<= 1) {
        int v = (t >= d) ? sums[t - d] : 0;
        __syncthreads();
        sums[t] += v;
        __syncthreads();
    }
    int run = (t > 0) ? sums[t - 1] : 0;
    for (int i = lo; i < hi; ++i) {
        offs[i] = run;
        cursor[i] = run;
        run += counts[i];
    }
    if (t == 1023) offs[N] = sums[1023];
}

// csr_all[e] = uint4:
//   .x = j[0:17) | r0>>1 [17:19) | r1>>1 [19:21) | iv [21:24)
//   .y = o0[0:11) | o1[11:22) | odd[22]   (o0/o1 = r*128+ivd*32, h2 units, 32-c stride)
//   .z = fp16x2 {wu0*gv, wu0*fv}   (even u-row r0)
//   .w = fp16x2 {wu1*gv, wu1*fv}   (odd  u-row r1)
__global__ void edge_scatter(const int* __restrict__ ei, const int* __restrict__ ej,
                             const float* __restrict__ pos, int* __restrict__ cursor,
                             uint4* __restrict__ csr_all, int E) {
    int e = blockIdx.x * 256 + threadIdx.x;
    if (e >= E) return;
    int i = ei[e], j = ej[e];
    if (i == j) return;
    float dx = clampf(pos[i * 2 + 0] - pos[j * 2 + 0], -1.f, 1.f);
    float dy = clampf(pos[i * 2 + 1] - pos[j * 2 + 1], -1.f, 1.f);
    float r = sqrtf(dx * dx + dy * dy + 1e-12f);
    float u = clampf(2.f * r - 1.f, -1.f, 1.f);
    float v = atan2f(dy, dx) * 0.3183098861837907f;  // / pi
    float tu = (u + 1.f) * 3.5f;
    float tv = (v + 1.f) * 3.5f;
    int iu = min(6, max(0, (int)floorf(tu)));
    int iv = min(6, max(0, (int)floorf(tv)));
    float fu = clampf(tu - (float)iu, 0.f, 1.f);
    float fv = clampf(tv - (float)iv, 0.f, 1.f);
    bool even = (iu & 1) == 0;
    int rowi0 = even ? iu : iu + 1;  // even u-row
    int rowi1 = even ? iu + 1 : iu;  // odd u-row
    float wu0 = even ? (1.f - fu) : fu;
    float wu1 = even ? fu : (1.f - fu);
    float gv = 1.f - fv;
    int ivd = iv >> 1;
    unsigned o0 = (unsigned)(rowi0 * 128 + ivd * 32);
    unsigned o1 = (unsigned)(rowi1 * 128 + ivd * 32);
    unsigned offp = o0 | (o1 << 11) | ((unsigned)(iv & 1) << 22);
    unsigned a0 = (unsigned)__builtin_bit_cast(unsigned short, (_Float16)(wu0 * gv)) |
                  ((unsigned)__builtin_bit_cast(unsigned short, (_Float16)(wu0 * fv)) << 16);
    unsigned a1 = (unsigned)__builtin_bit_cast(unsigned short, (_Float16)(wu1 * gv)) |
                  ((unsigned)__builtin_bit_cast(unsigned short, (_Float16)(wu1 * fv)) << 16);
    int p = atomicAdd(&cursor[i], 1);
    csr_all[p] = make_uint4(
        (unsigned)j | ((unsigned)(rowi0 >> 1) << 17) | ((unsigned)(rowi1 >> 1) << 19) |
            ((unsigned)iv << 21),
        offp, a0, a1);
}

// ---------------------------------------------------------------------------
// Layers 1..2 (CIN=64, COUT=64), c-split 2 ways (blockIdx.y = 32-channel half).
// 1024 threads = 16 waves = 16 nodes. Lane = (tap-half, channel): lanes 0..31
// accumulate the even-u-row taps, lanes 32..63 the odd-u-row taps -> per-lane
// LDS RMW chain halved (1 RMW even-iv, 2 odd-iv). Moments fp16, 65.25 KB LDS
// -> 2 blocks/CU = 32 waves/CU (was 1 block / 16 waves: the latency-hiding
// lever). GEMM: per-half K' = 2048 + 32 dense = 65 K-steps split over 16
// waves, f16 MFMA, partial-reduce in LDS, atomicAdd combine of the 2 halves
// onto a zeroed output (2 commutative f32 adds onto 0 -> bitwise determin.).
// MODE 1: relu in, out = conv(+dense) + cb + fb ; MODE 2: + residual x
template <int MODE>
__global__ __launch_bounds__(1024, 8) void conv64_mfma(
    const float* __restrict__ x, const _Float16* __restrict__ Wh,
    const float* __restrict__ cb, const float* __restrict__ fb,
    const int* __restrict__ offs, const uint4* __restrict__ csr_all,
    float* __restrict__ out, int nNodes) {
    constexpr int TM = 16;
    constexpr int KSTEPS = 65;
    constexpr int RSH = 2088;       // halfs per node row (4176 B), 16B aligned
    constexpr int RSD = RSH / 2;    // h2 per row = 1044
    extern __shared__ float mom[];  // 16 * 4176 B = 66816 B
    const int tid = threadIdx.x;
    const int w = tid >> 6;
    const int lane = tid & 63;
    const int half = lane >> 5;
    const int cl = lane & 31;
    const int base = blockIdx.x * TM;
    const int n = base + w;
    const int cofs = blockIdx.y * 32;

    {  // zero moments: 66816 B / 16 = 4176 float4
        float4 z = make_float4(0.f, 0.f, 0.f, 0.f);
        float4* m4 = (float4*)mom;
        for (int i = tid; i < TM * RSH / 8; i += 1024) m4[i] = z;
    }
    __syncthreads();

    // ---- scatter (one wave per node; both lane halves read the same 128B x
    // slice -> single coalesced transaction; each half owns one u-row's taps)
    if (n < nNodes) {
        const int e0 = offs[n], e1 = offs[n + 1];
        h2* momn2 = (h2*)mom + w * RSD;
        for (int b = e0; b < e1; b += 4) {
            uint4 ca[4];
            float xv[4];
#pragma unroll
            for (int u = 0; u < 4; ++u) {
                int e = b + u;
                bool ok = e < e1;
                ca[u] = csr_all[ok ? e : e0];
                xv[u] = ok ? 1.f : 0.f;
            }
#pragma unroll
            for (int u = 0; u < 4; ++u) {
                int j = ca[u].x & 0x1FFFF;
                xv[u] *= fmaxf(x[j * 64 + cofs + cl], 0.f);
            }
#pragma unroll
            for (int u = 0; u < 4; ++u) {
                unsigned y = ca[u].y;
                int o = half ? (int)((y >> 11) & 0x7FF) : (int)(y & 0x7FF);
                unsigned wbits = half ? ca[u].w : ca[u].z;
                _Float16 xh = (_Float16)xv[u];
                h2 xh2 = {xh, xh};
                h2 v = xh2 * __builtin_bit_cast(h2, wbits);
                h2* bp = momn2 + o + cl;
                if (!(y >> 22)) {  // wave-uniform branch (even iv)
                    bp[0] += v;
                } else {  // odd iv: v-taps straddle the ivd boundary
                    unsigned uu = __builtin_bit_cast(unsigned, v);
                    bp[0] += __builtin_bit_cast(h2, uu << 16);
                    bp[32] += __builtin_bit_cast(h2, uu >> 16);
                }
            }
        }
        // dense row k' = 2048 + cl (this block's c-half of relu(x[n]))
        if (half == 0)
            ((_Float16*)mom)[w * RSH + 2048 + cl] = (_Float16)fmaxf(x[n * 64 + cofs + cl], 0.f);
    }

    // ---- GEMM: K-chunk for this wave (65 = 1*5 + 15*4)
    const int s0 = w * 4 + min(w, 1);
    const int s_end = s0 + 4 + (w < 1 ? 1 : 0);
    const int quad = lane >> 4;
    const _Float16* arow = (const _Float16*)mom + (lane & 15) * RSH;

    const uint4* Bp = (const uint4*)Wh + (size_t)blockIdx.y * 4 * KSTEPS * 64;
    uint4 b0[4], b1[4];
#pragma unroll
    for (int t = 0; t < 4; ++t) {  // prefetch before barrier
        b0[t] = Bp[((size_t)t * KSTEPS + s0) * 64 + lane];
        b1[t] = Bp[((size_t)t * KSTEPS + s0 + 1) * 64 + lane];
    }
    __syncthreads();
    f32x4 acc[4] = {{0, 0, 0, 0}, {0, 0, 0, 0}, {0, 0, 0, 0}, {0, 0, 0, 0}};
    for (int s = s0; s < s_end; ++s) {
        uint4 bq[4];
#pragma unroll
        for (int t = 0; t < 4; ++t) {
            bq[t] = b0[t];
            b0[t] = b1[t];
            if (s + 2 < s_end) b1[t] = Bp[((size_t)t * KSTEPS + s + 2) * 64 + lane];
        }
        h8 a = *(const h8*)(arow + s * 32 + quad * 8);
#pragma unroll
        for (int t = 0; t < 4; ++t)
            acc[t] = __builtin_amdgcn_mfma_f32_16x16x32_f16(a, __builtin_bit_cast(h8, bq[t]),
                                                            acc[t], 0, 0, 0);
    }
    __syncthreads();  // moments dead -> reuse as reduce scratch (64 KB)
    f32x4* red = (f32x4*)mom;
#pragma unroll
    for (int t = 0; t < 4; ++t) red[(w * 4 + t) * 64 + lane] = acc[t];
    __syncthreads();
    if (w < 4) {
        f32x4 s = {0, 0, 0, 0};
#pragma unroll
        for (int g = 0; g < 16; ++g) s += red[(g * 4 + w) * 64 + lane];
        const int co = w * 16 + (lane & 15);
#pragma unroll
        for (int i = 0; i < 4; ++i) {
            int nn = base + quad * 4 + i;
            if (nn < nNodes) {
                float res = s[i];
                if (blockIdx.y == 0) {
                    res += cb[co] + fb[co];
                    if (MODE == 2) res += x[nn * 64 + co];
                }
                atomicAdd(&out[nn * 64 + co], res);
            }
        }
    }
}

// ---------------------------------------------------------------------------
// Layer 3 (CIN=64, COUT=2): direct per-edge form, no moments/GEMM.
__global__ __launch_bounds__(1024, 4) void conv_last(
    const float* __restrict__ x, const float* __restrict__ cw3, const float* __restrict__ fw3,
    const float* __restrict__ cb3, const float* __restrict__ fb3,
    const int* __restrict__ offs, const uint4* __restrict__ csr_all,
    float* __restrict__ out, int nNodes) {
    constexpr int TM = 16;
    __shared__ float2 W2[4096];   // 32 KB
    __shared__ float2 FW2[64];    // 512 B
    const int tid = threadIdx.x;
    const int w = tid >> 6;
    const int lane = tid & 63;
    const int base = blockIdx.x * TM;
    const int n = base + w;

    {  // stage weights
        const float2* src = (const float2*)cw3;
        for (int d = tid; d < 4096; d += 1024) W2[d] = src[d];
        if (tid < 64) FW2[tid] = ((const float2*)fw3)[tid];
    }
    __syncthreads();

    float2 acc = make_float2(0.f, 0.f);
    if (n < nNodes) {
        const int e0 = offs[n], e1 = offs[n + 1];
        const int c = lane;
        for (int b = e0; b < e1; b += 4) {
            uint4 ca[4];
            float xv[4];
#pragma unroll
            for (int u = 0; u < 4; ++u) {
                int e = b + u;
                bool ok = e < e1;
                ca[u] = csr_all[ok ? e : e0];
                xv[u] = ok ? 1.f : 0.f;
            }
#pragma unroll
            for (int u = 0; u < 4; ++u) {
                int j = ca[u].x & 0x1FFFF;
                xv[u] *= fmaxf(x[j * 64 + c], 0.f);
            }
#pragma unroll
            for (int u = 0; u < 4; ++u) {
                int r0 = ((ca[u].x >> 17) & 3) << 1;
                int r1 = (((ca[u].x >> 19) & 3) << 1) + 1;
                int iv = (ca[u].x >> 21) & 7;
                h2 wh0 = __builtin_bit_cast(h2, ca[u].z);
                h2 wh1 = __builtin_bit_cast(h2, ca[u].w);
                float w00 = (float)wh0[0], w01 = (float)wh0[1];
                float w10 = (float)wh1[0], w11 = (float)wh1[1];
                int b00 = (r0 * 8 + iv) * 64 + c;
                int b10 = (r1 * 8 + iv) * 64 + c;
                float2 t00 = W2[b00], t01 = W2[b00 + 64];
                float2 t10 = W2[b10], t11 = W2[b10 + 64];
                float wsx = w00 * t00.x + w01 * t01.x + w10 * t10.x + w11 * t11.x;
                float wsy = w00 * t00.y + w01 * t01.y + w10 * t10.y + w11 * t11.y;
                acc.x += xv[u] * wsx;
                acc.y += xv[u] * wsy;
            }
        }
        // dense branch
        float xr = fmaxf(x[n * 64 + c], 0.f);
        float2 fwp = FW2[c];
        acc.x += xr * fwp.x;
        acc.y += xr * fwp.y;
    }
    // butterfly reduce over 64 lanes
#pragma unroll
    for (int d = 1; d < 64; d <<= 1) {
        acc.x += __shfl_xor(acc.x, d);
        acc.y += __shfl_xor(acc.y, d);
    }
    if (lane == 0 && n < nNodes) {
        out[n * 2 + 0] = (acc.x + cb3[0] + fb3[0]) * (1.f / 128.f);
        out[n * 2 + 1] = (acc.y + cb3[1] + fb3[1]) * (1.f / 128.f);
    }
}

// ---------------------------------------------------------------------------
// Layer 0 (CIN=4, no relu on input): direct per-edge form.
__global__ __launch_bounds__(1024, 4) void conv0_direct(
    const float* __restrict__ x, const float* __restrict__ cw0, const float* __restrict__ fw0,
    const float* __restrict__ cb0, const float* __restrict__ fb0,
    const int* __restrict__ offs, const uint4* __restrict__ csr_all,
    float* __restrict__ out, int nNodes) {
    constexpr int TM = 16;
    __shared__ float2 W0p[4096];  // 32 KB
    __shared__ float2 FW0p[64];   // [h*32+co] = (fw0[2h][co], fw0[2h+1][co])
    const int tid = threadIdx.x;
    const int w = tid >> 6;
    const int lane = tid & 63;
    const int base = blockIdx.x * TM;
    const int n = base + w;

    {  // stage W0 permuted
        for (int d = tid; d < 4096; d += 1024) {
            int co = d & 31;
            int h = (d >> 5) & 1;
            int bin = d >> 6;
            W0p[d] = make_float2(cw0[(bin * 4 + 2 * h) * 32 + co],
                                 cw0[(bin * 4 + 2 * h + 1) * 32 + co]);
        }
        if (tid < 64) {
            int co = tid & 31;
            int h = tid >> 5;
            FW0p[tid] = make_float2(fw0[(2 * h) * 32 + co], fw0[(2 * h + 1) * 32 + co]);
        }
    }
    __syncthreads();

    const int co = lane & 31;
    const int h = lane >> 5;
    float accC = 0.f, accL = 0.f;
    if (n < nNodes) {
        const int e0 = offs[n], e1 = offs[n + 1];
        for (int b = e0; b < e1; b += 4) {
            uint4 ca[4];
            float xc0[4], xc1[4];
#pragma unroll
            for (int u = 0; u < 4; ++u) {
                int e = b + u;
                bool ok = e < e1;
                ca[u] = csr_all[ok ? e : e0];
                xc0[u] = ok ? 1.f : 0.f;
            }
#pragma unroll
            for (int u = 0; u < 4; ++u) {
                int j = ca[u].x & 0x1FFFF;
                const float4 xj = *(const float4*)(x + j * 4);  // no relu (layer 0)
                float a = h ? xj.z : xj.x;
                float bb = h ? xj.w : xj.y;
                xc1[u] = xc0[u] * bb;
                xc0[u] = xc0[u] * a;
            }
#pragma unroll
            for (int u = 0; u < 4; ++u) {
                int r0 = ((ca[u].x >> 17) & 3) << 1;
                int r1 = (((ca[u].x >> 19) & 3) << 1) + 1;
                int iv = (ca[u].x >> 21) & 7;
                h2 wh0 = __builtin_bit_cast(h2, ca[u].z);
                h2 wh1 = __builtin_bit_cast(h2, ca[u].w);
                float w00 = (float)wh0[0], w01 = (float)wh0[1];
                float w10 = (float)wh1[0], w11 = (float)wh1[1];
                int i00 = ((r0 * 8 + iv) * 2 + h) * 32 + co;
                int i10 = ((r1 * 8 + iv) * 2 + h) * 32 + co;
                float2 t00 = W0p[i00], t01 = W0p[i00 + 64];
                float2 t10 = W0p[i10], t11 = W0p[i10 + 64];
                accC += w00 * (xc0[u] * t00.x + xc1[u] * t00.y);
                accC += w01 * (xc0[u] * t01.x + xc1[u] * t01.y);
                accC += w10 * (xc0[u] * t10.x + xc1[u] * t10.y);
                accC += w11 * (xc0[u] * t11.x + xc1[u] * t11.y);
            }
        }
        // lin branch (no relu)
        const float4 xn = *(const float4*)(x + n * 4);
        float a = h ? xn.z : xn.x;
        float bb = h ? xn.w : xn.y;
        float2 fwp = FW0p[h * 32 + co];
        accL = a * fwp.x + bb * fwp.y;
    }
    accC += __shfl_xor(accC, 32);
    accL += __shfl_xor(accL, 32);
    if (lane < 32 && n < nNodes) {
        out[n * 64 + co] = accL + fb0[co];
        out[n * 64 + 32 + co] = accC + cb0[co];
    }
}

extern "C" void kernel_launch(void* const* d_in, const int* in_sizes, int n_in,
                              void* d_out, int out_size, void* d_ws, size_t ws_size,
                              hipStream_t stream) {
    const float* pos = (const float*)d_in[0];
    const float* feat = (const float*)d_in[1];
    const int* ei = (const int*)d_in[2];
    const int* ej = (const int*)d_in[3];
    const float* cw0 = (const float*)d_in[4];
    const float* cb0 = (const float*)d_in[5];
    const float* fw0 = (const float*)d_in[6];
    const float* fb0 = (const float*)d_in[7];
    const float* cw1 = (const float*)d_in[8];
    const float* cb1 = (const float*)d_in[9];
    const float* fw1 = (const float*)d_in[10];
    const float* fb1 = (const float*)d_in[11];
    const float* cw2 = (const float*)d_in[12];
    const float* cb2 = (const float*)d_in[13];
    const float* fw2 = (const float*)d_in[14];
    const float* fb2 = (const float*)d_in[15];
    const float* cw3 = (const float*)d_in[16];
    const float* cb3 = (const float*)d_in[17];
    const float* fw3 = (const float*)d_in[18];
    const float* fb3 = (const float*)d_in[19];
    float* outp = (float*)d_out;

    const int N = in_sizes[0] / 2;
    const int E = in_sizes[2];

    char* wsp = (char*)d_ws;
    size_t off = 0;
    auto alloc = [&](size_t bytes) -> void* {
        void* p = wsp + off;
        off = (off + bytes + 255) & ~(size_t)255;
        return p;
    };
    int* counts = (int*)alloc((size_t)N * 4);
    int* offs = (int*)alloc((size_t)(N + 1) * 4);
    int* cursor = (int*)alloc((size_t)N * 4);
    uint4* csr_all = (uint4*)alloc((size_t)E * 16);
    float* ansA = (float*)alloc((size_t)N * 64 * 4);
    float* ansB = (float*)alloc((size_t)N * 64 * 4);
    _Float16* Wh1 = (_Float16*)alloc((size_t)2 * 4 * 65 * 512 * 2);
    _Float16* Wh2 = (_Float16*)alloc((size_t)2 * 4 * 65 * 512 * 2);
    (void)ws_size;
    (void)n_in;
    (void)out_size;

    const int BIG_LDS = 16 * 2088 * 2;  // 66816 B -> 2 blocks/CU
    hipFuncSetAttribute((const void*)&conv64_mfma<1>,
                        hipFuncAttributeMaxDynamicSharedMemorySize, BIG_LDS);
    hipFuncSetAttribute((const void*)&conv64_mfma<2>,
                        hipFuncAttributeMaxDynamicSharedMemorySize, BIG_LDS);

    zero_ints<<<dim3((N + 255) / 256), dim3(256), 0, stream>>>(counts, N);
    const int RT = 2 * 4 * 65 * 512;
    repack_wh<<<dim3((RT + 255) / 256), dim3(256), 0, stream>>>(cw1, fw1, Wh1, 64);
    repack_wh<<<dim3((RT + 255) / 256), dim3(256), 0, stream>>>(cw2, fw2, Wh2, 64);
    edge_hist<<<dim3((E + 255) / 256), dim3(256), 0, stream>>>(ei, ej, counts, E);
    scan_kernel<<<dim3(1), dim3(1024), 0, stream>>>(counts, offs, cursor, N);
    edge_scatter<<<dim3((E + 255) / 256), dim3(256), 0, stream>>>(ei, ej, pos, cursor, csr_all, E);

    const int nb = (N + 15) / 16;
    conv0_direct<<<dim3(nb), dim3(1024), 0, stream>>>(
        feat, cw0, fw0, cb0, fb0, offs, csr_all, ansA, N);
    // zero ansB, then both c-halves atomicAdd into it
    zero_ints<<<dim3((N * 64 + 255) / 256), dim3(256), 0, stream>>>((int*)ansB, N * 64);
    conv64_mfma<1><<<dim3(nb, 2), dim3(1024), BIG_LDS, stream>>>(
        ansA, Wh1, cb1, fb1, offs, csr_all, ansB, N);
    // ansA (conv0 output) is dead now -> zero it for layer 2's atomic output
    zero_ints<<<dim3((N * 64 + 255) / 256), dim3(256), 0, stream>>>((int*)ansA, N * 64);
    conv64_mfma<2><<<dim3(nb, 2), dim3(1024), BIG_LDS, stream>>>(
        ansB, Wh2, cb2, fb2, offs, csr_all, ansA, N);
    conv_last<<<dim3(nb), dim3(1024), 0, stream>>>(
        ansA, cw3, fw3, cb3, fb3, offs, csr_all, outp, N);
}

// Round 3
// 1165.136 us; speedup vs baseline: 1.8898x; 1.8898x over previous
//
#include <hip/hip_runtime.h>
#include <math.h>

typedef _Float16 h8 __attribute__((ext_vector_type(8)));
typedef _Float16 h2 __attribute__((ext_vector_type(2)));
typedef float f32x4 __attribute__((ext_vector_type(4)));

__device__ __forceinline__ float clampf(float x, float lo, float hi) {
    return fminf(fmaxf(x, lo), hi);
}

__global__ void zero_ints(int* __restrict__ p, int n) {
    int i = blockIdx.x * 256 + threadIdx.x;
    if (i < n) p[i] = 0;
}

// fp16 B-frag repack for CIN=64 layers, c-split (H = c-half) permuted k' layout:
// per half: k' < 2048: rowi = k'>>8; ivd = (k'>>6)&3; c' = (k'>>1)&31; slot = k'&1;
//            iv = ivd*2+slot; orig (k,c) = (rowi*8+iv, H*32+c')  -> cw
// k' >= 2048: fw row c = H*32 + (k'-2048)
// Wh linear idx = (((H*4 + t)*65 + s)*512) + l*8 + j ; kp = s*32 + (l>>4)*8 + j
__global__ void repack_wh(const float* __restrict__ cw, const float* __restrict__ fw,
                          _Float16* __restrict__ Wh, int COUT) {
    int idx = blockIdx.x * 256 + threadIdx.x;
    int total = 2 * 4 * 65 * 512;
    if (idx >= total) return;
    int j = idx & 7;
    int l = (idx >> 3) & 63;
    int rest = idx >> 9;
    int s = rest % 65;
    int r2 = rest / 65;
    int t = r2 & 3;
    int H = r2 >> 2;
    int kp = s * 32 + (l >> 4) * 8 + j;
    int co = t * 16 + (l & 15);
    float v = 0.f;
    if (co < COUT) {
        if (kp < 2048) {
            int rowi = kp >> 8;
            int ivd = (kp >> 6) & 3;
            int cp = (kp >> 1) & 31;
            int slot = kp & 1;
            int iv = ivd * 2 + slot;
            int c = H * 32 + cp;
            v = cw[((rowi * 8 + iv) * 64 + c) * COUT + co];
        } else {
            int c = H * 32 + (kp - 2048);
            v = fw[c * COUT + co];
        }
    }
    Wh[idx] = (_Float16)v;
}

__global__ void edge_hist(const int* __restrict__ ei, const int* __restrict__ ej,
                          int* __restrict__ counts, int E) {
    int e = blockIdx.x * 256 + threadIdx.x;
    if (e >= E) return;
    int i = ei[e], j = ej[e];
    if (i != j) atomicAdd(&counts[i], 1);
}

__global__ __launch_bounds__(1024) void scan_kernel(const int* __restrict__ counts,
                                                    int* __restrict__ offs,
                                                    int* __restrict__ cursor, int N) {
    __shared__ int sums[1024];
    const int t = threadIdx.x;
    const int per = (N + 1023) / 1024;
    const int lo = t * per;
    const int hi = min(lo + per, N);
    int s = 0;
    for (int i = lo; i < hi; ++i) s += counts[i];
    sums[t] = s;
    __syncthreads();
    for (int d = 1; d < 1024; d <<= 1) {
        int v = (t >= d) ? sums[t - d] : 0;
        __syncthreads();
        sums[t] += v;
        __syncthreads();
    }
    int run = (t > 0) ? sums[t - 1] : 0;
    for (int i = lo; i < hi; ++i) {
        offs[i] = run;
        cursor[i] = run;
        run += counts[i];
    }
    if (t == 1023) offs[N] = sums[1023];
}

// csr_all[e] = uint4:
//   .x = j[0:17) | r0>>1 [17:19) | r1>>1 [19:21) | iv [21:24)
//   .y = o0[0:11) | o1[11:22) | odd[22]   (o0/o1 = r*128+ivd*32, h2 units, 32-c stride)
//   .z = fp16x2 {wu0*gv, wu0*fv}   (even u-row r0)
//   .w = fp16x2 {wu1*gv, wu1*fv}   (odd  u-row r1)
__global__ void edge_scatter(const int* __restrict__ ei, const int* __restrict__ ej,
                             const float* __restrict__ pos, int* __restrict__ cursor,
                             uint4* __restrict__ csr_all, int E) {
    int e = blockIdx.x * 256 + threadIdx.x;
    if (e >= E) return;
    int i = ei[e], j = ej[e];
    if (i == j) return;
    float dx = clampf(pos[i * 2 + 0] - pos[j * 2 + 0], -1.f, 1.f);
    float dy = clampf(pos[i * 2 + 1] - pos[j * 2 + 1], -1.f, 1.f);
    float r = sqrtf(dx * dx + dy * dy + 1e-12f);
    float u = clampf(2.f * r - 1.f, -1.f, 1.f);
    float v = atan2f(dy, dx) * 0.3183098861837907f;  // / pi
    float tu = (u + 1.f) * 3.5f;
    float tv = (v + 1.f) * 3.5f;
    int iu = min(6, max(0, (int)floorf(tu)));
    int iv = min(6, max(0, (int)floorf(tv)));
    float fu = clampf(tu - (float)iu, 0.f, 1.f);
    float fv = clampf(tv - (float)iv, 0.f, 1.f);
    bool even = (iu & 1) == 0;
    int rowi0 = even ? iu : iu + 1;  // even u-row
    int rowi1 = even ? iu + 1 : iu;  // odd u-row
    float wu0 = even ? (1.f - fu) : fu;
    float wu1 = even ? fu : (1.f - fu);
    float gv = 1.f - fv;
    int ivd = iv >> 1;
    unsigned o0 = (unsigned)(rowi0 * 128 + ivd * 32);
    unsigned o1 = (unsigned)(rowi1 * 128 + ivd * 32);
    unsigned offp = o0 | (o1 << 11) | ((unsigned)(iv & 1) << 22);
    unsigned a0 = (unsigned)__builtin_bit_cast(unsigned short, (_Float16)(wu0 * gv)) |
                  ((unsigned)__builtin_bit_cast(unsigned short, (_Float16)(wu0 * fv)) << 16);
    unsigned a1 = (unsigned)__builtin_bit_cast(unsigned short, (_Float16)(wu1 * gv)) |
                  ((unsigned)__builtin_bit_cast(unsigned short, (_Float16)(wu1 * fv)) << 16);
    int p = atomicAdd(&cursor[i], 1);
    csr_all[p] = make_uint4(
        (unsigned)j | ((unsigned)(rowi0 >> 1) << 17) | ((unsigned)(rowi1 >> 1) << 19) |
            ((unsigned)iv << 21),
        offp, a0, a1);
}

// ---------------------------------------------------------------------------
// Layers 1..2 (CIN=64, COUT=64), c-split 2 ways (blockIdx.y = 32-channel half).
// 1024 threads = 16 waves = 16 nodes. Lane = (tap-half, channel): lanes 0..31
// accumulate the even-u-row taps, lanes 32..63 the odd-u-row taps -> per-lane
// LDS RMW chain halved. Moments fp16, 65.25 KB LDS -> 2 blocks/CU = 32
// waves/CU IF actual VGPR use <= 64 (incl AGPR, unified file). launch_bounds
// kept at (1024,4): round-2 showed forcing 8 waves/EU makes the allocator
// spill (VGPR=32 + 1.37 GB scratch writes). GEMM deliberately has NO register
// B-prefetch (B is 266 KB, L2-resident, reused by all blocks; TLP hides L2
// latency) to keep live state ~45-55 regs. Partial-reduce in LDS, atomicAdd
// combine of the 2 halves onto a zeroed output (deterministic: 2 commutative
// f32 adds onto 0).
// MODE 1: relu in, out = conv(+dense) + cb + fb ; MODE 2: + residual x
template <int MODE>
__global__ __launch_bounds__(1024, 4) void conv64_mfma(
    const float* __restrict__ x, const _Float16* __restrict__ Wh,
    const float* __restrict__ cb, const float* __restrict__ fb,
    const int* __restrict__ offs, const uint4* __restrict__ csr_all,
    float* __restrict__ out, int nNodes) {
    constexpr int TM = 16;
    constexpr int KSTEPS = 65;
    constexpr int RSH = 2088;       // halfs per node row (4176 B), 16B aligned
    constexpr int RSD = RSH / 2;    // h2 per row = 1044
    extern __shared__ float mom[];  // 16 * 4176 B = 66816 B
    const int tid = threadIdx.x;
    const int w = tid >> 6;
    const int lane = tid & 63;
    const int half = lane >> 5;
    const int cl = lane & 31;
    const int base = blockIdx.x * TM;
    const int n = base + w;
    const int cofs = blockIdx.y * 32;

    {  // zero moments: 66816 B / 16 = 4176 float4
        float4 z = make_float4(0.f, 0.f, 0.f, 0.f);
        float4* m4 = (float4*)mom;
        for (int i = tid; i < TM * RSH / 8; i += 1024) m4[i] = z;
    }
    __syncthreads();

    // ---- scatter (one wave per node; both lane halves read the same 128B x
    // slice -> single coalesced transaction; each half owns one u-row's taps)
    if (n < nNodes) {
        const int e0 = offs[n], e1 = offs[n + 1];
        h2* momn2 = (h2*)mom + w * RSD;
        for (int b = e0; b < e1; b += 4) {
            uint4 ca[4];
            float xv[4];
#pragma unroll
            for (int u = 0; u < 4; ++u) {
                int e = b + u;
                bool ok = e < e1;
                ca[u] = csr_all[ok ? e : e0];
                xv[u] = ok ? 1.f : 0.f;
            }
#pragma unroll
            for (int u = 0; u < 4; ++u) {
                int j = ca[u].x & 0x1FFFF;
                xv[u] *= fmaxf(x[j * 64 + cofs + cl], 0.f);
            }
#pragma unroll
            for (int u = 0; u < 4; ++u) {
                unsigned y = ca[u].y;
                int o = half ? (int)((y >> 11) & 0x7FF) : (int)(y & 0x7FF);
                unsigned wbits = half ? ca[u].w : ca[u].z;
                _Float16 xh = (_Float16)xv[u];
                h2 xh2 = {xh, xh};
                h2 v = xh2 * __builtin_bit_cast(h2, wbits);
                h2* bp = momn2 + o + cl;
                if (!(y >> 22)) {  // wave-uniform branch (even iv)
                    bp[0] += v;
                } else {  // odd iv: v-taps straddle the ivd boundary
                    unsigned uu = __builtin_bit_cast(unsigned, v);
                    bp[0] += __builtin_bit_cast(h2, uu << 16);
                    bp[32] += __builtin_bit_cast(h2, uu >> 16);
                }
            }
        }
        // dense row k' = 2048 + cl (this block's c-half of relu(x[n]))
        if (half == 0)
            ((_Float16*)mom)[w * RSH + 2048 + cl] = (_Float16)fmaxf(x[n * 64 + cofs + cl], 0.f);
    }

    // ---- GEMM: K-chunk for this wave (65 = 1*5 + 15*4), no reg prefetch
    const int s0 = w * 4 + min(w, 1);
    const int s_end = s0 + 4 + (w < 1 ? 1 : 0);
    const int quad = lane >> 4;
    const _Float16* arow = (const _Float16*)mom + (lane & 15) * RSH;
    const uint4* Bp = (const uint4*)Wh + (size_t)blockIdx.y * 4 * KSTEPS * 64 + lane;

    __syncthreads();
    f32x4 acc[4] = {{0, 0, 0, 0}, {0, 0, 0, 0}, {0, 0, 0, 0}, {0, 0, 0, 0}};
    for (int s = s0; s < s_end; ++s) {
        uint4 bq[4];
#pragma unroll
        for (int t = 0; t < 4; ++t) bq[t] = Bp[((size_t)t * KSTEPS + s) * 64];
        h8 a = *(const h8*)(arow + s * 32 + quad * 8);
#pragma unroll
        for (int t = 0; t < 4; ++t)
            acc[t] = __builtin_amdgcn_mfma_f32_16x16x32_f16(a, __builtin_bit_cast(h8, bq[t]),
                                                            acc[t], 0, 0, 0);
    }
    __syncthreads();  // moments dead -> reuse as reduce scratch (64 KB)
    f32x4* red = (f32x4*)mom;
#pragma unroll
    for (int t = 0; t < 4; ++t) red[(w * 4 + t) * 64 + lane] = acc[t];
    __syncthreads();
    if (w < 4) {
        f32x4 s = {0, 0, 0, 0};
#pragma unroll
        for (int g = 0; g < 16; ++g) s += red[(g * 4 + w) * 64 + lane];
        const int co = w * 16 + (lane & 15);
#pragma unroll
        for (int i = 0; i < 4; ++i) {
            int nn = base + quad * 4 + i;
            if (nn < nNodes) {
                float res = s[i];
                if (blockIdx.y == 0) {
                    res += cb[co] + fb[co];
                    if (MODE == 2) res += x[nn * 64 + co];
                }
                atomicAdd(&out[nn * 64 + co], res);
            }
        }
    }
}

// ---------------------------------------------------------------------------
// Layer 3 (CIN=64, COUT=2): direct per-edge form, no moments/GEMM.
__global__ __launch_bounds__(1024, 4) void conv_last(
    const float* __restrict__ x, const float* __restrict__ cw3, const float* __restrict__ fw3,
    const float* __restrict__ cb3, const float* __restrict__ fb3,
    const int* __restrict__ offs, const uint4* __restrict__ csr_all,
    float* __restrict__ out, int nNodes) {
    constexpr int TM = 16;
    __shared__ float2 W2[4096];   // 32 KB
    __shared__ float2 FW2[64];    // 512 B
    const int tid = threadIdx.x;
    const int w = tid >> 6;
    const int lane = tid & 63;
    const int base = blockIdx.x * TM;
    const int n = base + w;

    {  // stage weights
        const float2* src = (const float2*)cw3;
        for (int d = tid; d < 4096; d += 1024) W2[d] = src[d];
        if (tid < 64) FW2[tid] = ((const float2*)fw3)[tid];
    }
    __syncthreads();

    float2 acc = make_float2(0.f, 0.f);
    if (n < nNodes) {
        const int e0 = offs[n], e1 = offs[n + 1];
        const int c = lane;
        for (int b = e0; b < e1; b += 4) {
            uint4 ca[4];
            float xv[4];
#pragma unroll
            for (int u = 0; u < 4; ++u) {
                int e = b + u;
                bool ok = e < e1;
                ca[u] = csr_all[ok ? e : e0];
                xv[u] = ok ? 1.f : 0.f;
            }
#pragma unroll
            for (int u = 0; u < 4; ++u) {
                int j = ca[u].x & 0x1FFFF;
                xv[u] *= fmaxf(x[j * 64 + c], 0.f);
            }
#pragma unroll
            for (int u = 0; u < 4; ++u) {
                int r0 = ((ca[u].x >> 17) & 3) << 1;
                int r1 = (((ca[u].x >> 19) & 3) << 1) + 1;
                int iv = (ca[u].x >> 21) & 7;
                h2 wh0 = __builtin_bit_cast(h2, ca[u].z);
                h2 wh1 = __builtin_bit_cast(h2, ca[u].w);
                float w00 = (float)wh0[0], w01 = (float)wh0[1];
                float w10 = (float)wh1[0], w11 = (float)wh1[1];
                int b00 = (r0 * 8 + iv) * 64 + c;
                int b10 = (r1 * 8 + iv) * 64 + c;
                float2 t00 = W2[b00], t01 = W2[b00 + 64];
                float2 t10 = W2[b10], t11 = W2[b10 + 64];
                float wsx = w00 * t00.x + w01 * t01.x + w10 * t10.x + w11 * t11.x;
                float wsy = w00 * t00.y + w01 * t01.y + w10 * t10.y + w11 * t11.y;
                acc.x += xv[u] * wsx;
                acc.y += xv[u] * wsy;
            }
        }
        // dense branch
        float xr = fmaxf(x[n * 64 + c], 0.f);
        float2 fwp = FW2[c];
        acc.x += xr * fwp.x;
        acc.y += xr * fwp.y;
    }
    // butterfly reduce over 64 lanes
#pragma unroll
    for (int d = 1; d < 64; d <<= 1) {
        acc.x += __shfl_xor(acc.x, d);
        acc.y += __shfl_xor(acc.y, d);
    }
    if (lane == 0 && n < nNodes) {
        out[n * 2 + 0] = (acc.x + cb3[0] + fb3[0]) * (1.f / 128.f);
        out[n * 2 + 1] = (acc.y + cb3[1] + fb3[1]) * (1.f / 128.f);
    }
}

// ---------------------------------------------------------------------------
// Layer 0 (CIN=4, no relu on input): direct per-edge form.
__global__ __launch_bounds__(1024, 4) void conv0_direct(
    const float* __restrict__ x, const float* __restrict__ cw0, const float* __restrict__ fw0,
    const float* __restrict__ cb0, const float* __restrict__ fb0,
    const int* __restrict__ offs, const uint4* __restrict__ csr_all,
    float* __restrict__ out, int nNodes) {
    constexpr int TM = 16;
    __shared__ float2 W0p[4096];  // 32 KB
    __shared__ float2 FW0p[64];   // [h*32+co] = (fw0[2h][co], fw0[2h+1][co])
    const int tid = threadIdx.x;
    const int w = tid >> 6;
    const int lane = tid & 63;
    const int base = blockIdx.x * TM;
    const int n = base + w;

    {  // stage W0 permuted
        for (int d = tid; d < 4096; d += 1024) {
            int co = d & 31;
            int h = (d >> 5) & 1;
            int bin = d >> 6;
            W0p[d] = make_float2(cw0[(bin * 4 + 2 * h) * 32 + co],
                                 cw0[(bin * 4 + 2 * h + 1) * 32 + co]);
        }
        if (tid < 64) {
            int co = tid & 31;
            int h = tid >> 5;
            FW0p[tid] = make_float2(fw0[(2 * h) * 32 + co], fw0[(2 * h + 1) * 32 + co]);
        }
    }
    __syncthreads();

    const int co = lane & 31;
    const int h = lane >> 5;
    float accC = 0.f, accL = 0.f;
    if (n < nNodes) {
        const int e0 = offs[n], e1 = offs[n + 1];
        for (int b = e0; b < e1; b += 4) {
            uint4 ca[4];
            float xc0[4], xc1[4];
#pragma unroll
            for (int u = 0; u < 4; ++u) {
                int e = b + u;
                bool ok = e < e1;
                ca[u] = csr_all[ok ? e : e0];
                xc0[u] = ok ? 1.f : 0.f;
            }
#pragma unroll
            for (int u = 0; u < 4; ++u) {
                int j = ca[u].x & 0x1FFFF;
                const float4 xj = *(const float4*)(x + j * 4);  // no relu (layer 0)
                float a = h ? xj.z : xj.x;
                float bb = h ? xj.w : xj.y;
                xc1[u] = xc0[u] * bb;
                xc0[u] = xc0[u] * a;
            }
#pragma unroll
            for (int u = 0; u < 4; ++u) {
                int r0 = ((ca[u].x >> 17) & 3) << 1;
                int r1 = (((ca[u].x >> 19) & 3) << 1) + 1;
                int iv = (ca[u].x >> 21) & 7;
                h2 wh0 = __builtin_bit_cast(h2, ca[u].z);
                h2 wh1 = __builtin_bit_cast(h2, ca[u].w);
                float w00 = (float)wh0[0], w01 = (float)wh0[1];
                float w10 = (float)wh1[0], w11 = (float)wh1[1];
                int i00 = ((r0 * 8 + iv) * 2 + h) * 32 + co;
                int i10 = ((r1 * 8 + iv) * 2 + h) * 32 + co;
                float2 t00 = W0p[i00], t01 = W0p[i00 + 64];
                float2 t10 = W0p[i10], t11 = W0p[i10 + 64];
                accC += w00 * (xc0[u] * t00.x + xc1[u] * t00.y);
                accC += w01 * (xc0[u] * t01.x + xc1[u] * t01.y);
                accC += w10 * (xc0[u] * t10.x + xc1[u] * t10.y);
                accC += w11 * (xc0[u] * t11.x + xc1[u] * t11.y);
            }
        }
        // lin branch (no relu)
        const float4 xn = *(const float4*)(x + n * 4);
        float a = h ? xn.z : xn.x;
        float bb = h ? xn.w : xn.y;
        float2 fwp = FW0p[h * 32 + co];
        accL = a * fwp.x + bb * fwp.y;
    }
    accC += __shfl_xor(accC, 32);
    accL += __shfl_xor(accL, 32);
    if (lane < 32 && n < nNodes) {
        out[n * 64 + co] = accL + fb0[co];
        out[n * 64 + 32 + co] = accC + cb0[co];
    }
}

extern "C" void kernel_launch(void* const* d_in, const int* in_sizes, int n_in,
                              void* d_out, int out_size, void* d_ws, size_t ws_size,
                              hipStream_t stream) {
    const float* pos = (const float*)d_in[0];
    const float* feat = (const float*)d_in[1];
    const int* ei = (const int*)d_in[2];
    const int* ej = (const int*)d_in[3];
    const float* cw0 = (const float*)d_in[4];
    const float* cb0 = (const float*)d_in[5];
    const float* fw0 = (const float*)d_in[6];
    const float* fb0 = (const float*)d_in[7];
    const float* cw1 = (const float*)d_in[8];
    const float* cb1 = (const float*)d_in[9];
    const float* fw1 = (const float*)d_in[10];
    const float* fb1 = (const float*)d_in[11];
    const float* cw2 = (const float*)d_in[12];
    const float* cb2 = (const float*)d_in[13];
    const float* fw2 = (const float*)d_in[14];
    const float* fb2 = (const float*)d_in[15];
    const float* cw3 = (const float*)d_in[16];
    const float* cb3 = (const float*)d_in[17];
    const float* fw3 = (const float*)d_in[18];
    const float* fb3 = (const float*)d_in[19];
    float* outp = (float*)d_out;

    const int N = in_sizes[0] / 2;
    const int E = in_sizes[2];

    char* wsp = (char*)d_ws;
    size_t off = 0;
    auto alloc = [&](size_t bytes) -> void* {
        void* p = wsp + off;
        off = (off + bytes + 255) & ~(size_t)255;
        return p;
    };
    int* counts = (int*)alloc((size_t)N * 4);
    int* offs = (int*)alloc((size_t)(N + 1) * 4);
    int* cursor = (int*)alloc((size_t)N * 4);
    uint4* csr_all = (uint4*)alloc((size_t)E * 16);
    float* ansA = (float*)alloc((size_t)N * 64 * 4);
    float* ansB = (float*)alloc((size_t)N * 64 * 4);
    _Float16* Wh1 = (_Float16*)alloc((size_t)2 * 4 * 65 * 512 * 2);
    _Float16* Wh2 = (_Float16*)alloc((size_t)2 * 4 * 65 * 512 * 2);
    (void)ws_size;
    (void)n_in;
    (void)out_size;

    const int BIG_LDS = 16 * 2088 * 2;  // 66816 B -> 2 blocks/CU (if VGPR <= 64)
    hipFuncSetAttribute((const void*)&conv64_mfma<1>,
                        hipFuncAttributeMaxDynamicSharedMemorySize, BIG_LDS);
    hipFuncSetAttribute((const void*)&conv64_mfma<2>,
                        hipFuncAttributeMaxDynamicSharedMemorySize, BIG_LDS);

    zero_ints<<<dim3((N + 255) / 256), dim3(256), 0, stream>>>(counts, N);
    const int RT = 2 * 4 * 65 * 512;
    repack_wh<<<dim3((RT + 255) / 256), dim3(256), 0, stream>>>(cw1, fw1, Wh1, 64);
    repack_wh<<<dim3((RT + 255) / 256), dim3(256), 0, stream>>>(cw2, fw2, Wh2, 64);
    edge_hist<<<dim3((E + 255) / 256), dim3(256), 0, stream>>>(ei, ej, counts, E);
    scan_kernel<<<dim3(1), dim3(1024), 0, stream>>>(counts, offs, cursor, N);
    edge_scatter<<<dim3((E + 255) / 256), dim3(256), 0, stream>>>(ei, ej, pos, cursor, csr_all, E);

    const int nb = (N + 15) / 16;
    conv0_direct<<<dim3(nb), dim3(1024), 0, stream>>>(
        feat, cw0, fw0, cb0, fb0, offs, csr_all, ansA, N);
    // zero ansB, then both c-halves atomicAdd into it
    zero_ints<<<dim3((N * 64 + 255) / 256), dim3(256), 0, stream>>>((int*)ansB, N * 64);
    conv64_mfma<1><<<dim3(nb, 2), dim3(1024), BIG_LDS, stream>>>(
        ansA, Wh1, cb1, fb1, offs, csr_all, ansB, N);
    // ansA (conv0 output) is dead now -> zero it for layer 2's atomic output
    zero_ints<<<dim3((N * 64 + 255) / 256), dim3(256), 0, stream>>>((int*)ansA, N * 64);
    conv64_mfma<2><<<dim3(nb, 2), dim3(1024), BIG_LDS, stream>>>(
        ansB, Wh2, cb2, fb2, offs, csr_all, ansA, N);
    conv_last<<<dim3(nb), dim3(1024), 0, stream>>>(
        ansA, cw3, fw3, cb3, fb3, offs, csr_all, outp, N);
}

// Round 4
// 915.300 us; speedup vs baseline: 2.4056x; 1.2730x over previous
//
#include <hip/hip_runtime.h>
#include <math.h>

typedef _Float16 h8 __attribute__((ext_vector_type(8)));
typedef _Float16 h2 __attribute__((ext_vector_type(2)));
typedef float f32x4 __attribute__((ext_vector_type(4)));

__device__ __forceinline__ float clampf(float x, float lo, float hi) {
    return fminf(fmaxf(x, lo), hi);
}

__global__ void zero_ints(int* __restrict__ p, int n) {
    int i = blockIdx.x * 256 + threadIdx.x;
    if (i < n) p[i] = 0;
}

// fp16 B repack for CIN=64 layers, frag-major physical k' (= p) layout:
// p < 4096:  tile = p>>8 (mt = tile>>2, ct = tile&3); g = (p>>6)&3;
//            m = (p>>2)&15; i = p&3; bin = mt*16+g*4+i; c = ct*16+m -> cw[bin][c]
// p >= 4096: fw row c = p-4096   (4096..4159; 130 K-steps * 32 = 4160 exactly)
// Wh half idx = ((t*130 + s)*512) + l*8 + j8 ; p = s*32 + (l>>4)*8 + j8
__global__ void repack_wh(const float* __restrict__ cw, const float* __restrict__ fw,
                          _Float16* __restrict__ Wh) {
    int idx = blockIdx.x * 256 + threadIdx.x;
    int total = 4 * 130 * 512;
    if (idx >= total) return;
    int j8 = idx & 7;
    int l = (idx >> 3) & 63;
    int rest = idx >> 9;
    int s = rest % 130;
    int t = rest / 130;
    int p = s * 32 + ((l >> 4) * 8) + j8;
    int co = t * 16 + (l & 15);
    float v = 0.f;
    if (p < 4096) {
        int tile = p >> 8;
        int g = (p >> 6) & 3;
        int m = (p >> 2) & 15;
        int i = p & 3;
        int mt = tile >> 2;
        int ct = tile & 3;
        int bin = mt * 16 + g * 4 + i;
        int c = ct * 16 + m;
        v = cw[(bin * 64 + c) * 64 + co];
    } else if (p < 4160) {
        v = fw[(p - 4096) * 64 + co];
    }
    Wh[idx] = (_Float16)v;
}

__global__ void edge_hist(const int* __restrict__ ei, const int* __restrict__ ej,
                          int* __restrict__ counts, int E) {
    int e = blockIdx.x * 256 + threadIdx.x;
    if (e >= E) return;
    int i = ei[e], j = ej[e];
    if (i != j) atomicAdd(&counts[i], 1);
}

__global__ __launch_bounds__(1024) void scan_kernel(const int* __restrict__ counts,
                                                    int* __restrict__ offs,
                                                    int* __restrict__ cursor, int N) {
    __shared__ int sums[1024];
    const int t = threadIdx.x;
    const int per = (N + 1023) / 1024;
    const int lo = t * per;
    const int hi = min(lo + per, N);
    int s = 0;
    for (int i = lo; i < hi; ++i) s += counts[i];
    sums[t] = s;
    __syncthreads();
    for (int d = 1; d < 1024; d <<= 1) {
        int v = (t >= d) ? sums[t - d] : 0;
        __syncthreads();
        sums[t] += v;
        __syncthreads();
    }
    int run = (t > 0) ? sums[t - 1] : 0;
    for (int i = lo; i < hi; ++i) {
        offs[i] = run;
        cursor[i] = run;
        run += counts[i];
    }
    if (t == 1023) offs[N] = sums[1023];
}

// csr_all[e] = uint4:
//   .x = j[0:17) | r0>>1 [17:19) | r1>>1 [19:21) | iv [21:24)
//   .y = (legacy offsets, unused by conv64 now; kept for conv0/conv_last)
//   .z = fp16x2 {wu0*gv, wu0*fv}   (even u-row r0 taps at iv, iv+1)
//   .w = fp16x2 {wu1*gv, wu1*fv}   (odd  u-row r1 taps at iv, iv+1)
__global__ void edge_scatter(const int* __restrict__ ei, const int* __restrict__ ej,
                             const float* __restrict__ pos, int* __restrict__ cursor,
                             uint4* __restrict__ csr_all, int E) {
    int e = blockIdx.x * 256 + threadIdx.x;
    if (e >= E) return;
    int i = ei[e], j = ej[e];
    if (i == j) return;
    float dx = clampf(pos[i * 2 + 0] - pos[j * 2 + 0], -1.f, 1.f);
    float dy = clampf(pos[i * 2 + 1] - pos[j * 2 + 1], -1.f, 1.f);
    float r = sqrtf(dx * dx + dy * dy + 1e-12f);
    float u = clampf(2.f * r - 1.f, -1.f, 1.f);
    float v = atan2f(dy, dx) * 0.3183098861837907f;  // / pi
    float tu = (u + 1.f) * 3.5f;
    float tv = (v + 1.f) * 3.5f;
    int iu = min(6, max(0, (int)floorf(tu)));
    int iv = min(6, max(0, (int)floorf(tv)));
    float fu = clampf(tu - (float)iu, 0.f, 1.f);
    float fv = clampf(tv - (float)iv, 0.f, 1.f);
    bool even = (iu & 1) == 0;
    int rowi0 = even ? iu : iu + 1;  // even u-row
    int rowi1 = even ? iu + 1 : iu;  // odd u-row
    float wu0 = even ? (1.f - fu) : fu;
    float wu1 = even ? fu : (1.f - fu);
    float gv = 1.f - fv;
    int ivd = iv >> 1;
    unsigned o0 = (unsigned)(rowi0 * 256 + ivd * 64);
    unsigned o1 = (unsigned)(rowi1 * 256 + ivd * 64);
    unsigned offp = o0 | (o1 << 11) | ((unsigned)(iv & 1) << 22);
    unsigned a0 = (unsigned)__builtin_bit_cast(unsigned short, (_Float16)(wu0 * gv)) |
                  ((unsigned)__builtin_bit_cast(unsigned short, (_Float16)(wu0 * fv)) << 16);
    unsigned a1 = (unsigned)__builtin_bit_cast(unsigned short, (_Float16)(wu1 * gv)) |
                  ((unsigned)__builtin_bit_cast(unsigned short, (_Float16)(wu1 * fv)) << 16);
    int p = atomicAdd(&cursor[i], 1);
    csr_all[p] = make_uint4(
        (unsigned)j | ((unsigned)(rowi0 >> 1) << 17) | ((unsigned)(rowi1 >> 1) << 19) |
            ((unsigned)iv << 21),
        offp, a0, a1);
}

// ---------------------------------------------------------------------------
// Layers 1..2 (CIN=64, COUT=64) — MFMA moment computation.
// Phase 1 (per wave = per node): K-tiles of 32 edges.
//   A = basis [64 bins x 32 e] fp16 in LDS, zeroed + 4-tap sparse scatter.
//       layout: addr = bin*32 + (((e>>3)+(bin>>1))&3)*8 + (e&7)  (2-way reads)
//   B = gathered xh rows [32 e x 64 c] fp16 in LDS, subtiled:
//       addr = ((e>>2)*4 + (c>>4))*64 + ((e&3)^(e>>3))*16 + (c&15) (b128 writes
//       conflict-free, b16 frag reads 2-way)
//   C = mom [64 bins x 64 c] f32 in 16 acc tiles (f32->fp16 once at writeback;
//       f32 accumulation is MORE precise than old per-edge fp16 LDS RMW).
// Writeback into frag-major mom row p = tile*256 + g*64 + m*4 + i (b64 writes).
// Dense row p = 4096+c = xh[n] (already relu'd fp16, same numerics as before).
// Phase 2: second GEMM (mom x Wh), K=130 steps split over 16 waves — the
// proven round-0 structure. LDS 133 KB (staging overlays mom rows, lifetime-
// disjoint per wave, no extra barrier needed before per-wave writeback).
// MODE 1: out32 = gemm + cb + fb, xh_out = fp16(relu(out32))
// MODE 2: out32 = gemm + cb + fb + x32 (residual), no xh_out
template <int MODE>
__global__ __launch_bounds__(1024, 4) void conv64_mfma(
    const _Float16* __restrict__ xh, const float* __restrict__ x32,
    const _Float16* __restrict__ Wh,
    const float* __restrict__ cb, const float* __restrict__ fb,
    const int* __restrict__ offs, const uint4* __restrict__ csr_all,
    float* __restrict__ out32, _Float16* __restrict__ xh_out, int nNodes) {
    constexpr int TM = 16;
    constexpr int KSTEPS = 130;
    constexpr int RSH = 4168;            // halfs per node row (8336 B, odd*16B)
    extern __shared__ _Float16 smem[];   // 16 * 4168 * 2 = 133376 B
    const int tid = threadIdx.x;
    const int w = tid >> 6;
    const int lane = tid & 63;
    const int base = blockIdx.x * TM;
    const int n = base + w;

    _Float16* Ast = smem + w * RSH;      // 2048 halfs: basis tile
    _Float16* Bst = Ast + 2048;          // 2048 halfs: x tile

    f32x4 acc[16] = {{0, 0, 0, 0}, {0, 0, 0, 0}, {0, 0, 0, 0}, {0, 0, 0, 0},
                     {0, 0, 0, 0}, {0, 0, 0, 0}, {0, 0, 0, 0}, {0, 0, 0, 0},
                     {0, 0, 0, 0}, {0, 0, 0, 0}, {0, 0, 0, 0}, {0, 0, 0, 0},
                     {0, 0, 0, 0}, {0, 0, 0, 0}, {0, 0, 0, 0}, {0, 0, 0, 0}};

    if (n < nNodes) {
        const int e0 = offs[n], e1 = offs[n + 1];
        const int half = lane >> 5;
        const int el = lane & 31;
        for (int bs = e0; bs < e1; bs += 32) {
            {  // zero A (4 KB)
                uint4 z4 = make_uint4(0, 0, 0, 0);
#pragma unroll
                for (int zz = 0; zz < 4; ++zz) ((uint4*)Ast)[zz * 64 + lane] = z4;
            }
            // decode + sparse A scatter: lanes 0..31 = even-row taps (z),
            // lanes 32..63 = odd-row taps (w). Disjoint bins -> no collisions.
            int e = bs + el;
            bool ok = e < e1;
            uint4 ca = csr_all[ok ? e : e0];
            int jme = ok ? (int)(ca.x & 0x1FFFF) : -1;
            {
                int iv = (ca.x >> 21) & 7;
                int rowi = half ? (int)((((ca.x >> 19) & 3) << 1) + 1)
                                : (int)(((ca.x >> 17) & 3) << 1);
                h2 wts = __builtin_bit_cast(h2, half ? ca.w : ca.z);
                if (ok) {
                    int bin0 = rowi * 8 + iv;
                    int bin1 = bin0 + 1;  // iv <= 6 so stays within the row
                    int a0 = bin0 * 32 + (((el >> 3) + (bin0 >> 1)) & 3) * 8 + (el & 7);
                    int a1 = bin1 * 32 + (((el >> 3) + (bin1 >> 1)) & 3) * 8 + (el & 7);
                    Ast[a0] = wts[0];
                    Ast[a1] = wts[1];
                }
            }
            // B gather: 4 iters, each stages 8 edges x 64 ch (b128, confl-free)
#pragma unroll
            for (int it = 0; it < 4; ++it) {
                int ee = it * 8 + (lane >> 3);
                int jj = __shfl(jme, ee);
                int c0 = (lane & 7) * 8;
                uint4 bv = make_uint4(0, 0, 0, 0);
                if (jj >= 0) bv = *(const uint4*)(xh + (size_t)jj * 64 + c0);
                int sub = (ee >> 2) * 4 + (c0 >> 4);
                int row = (ee & 3) ^ it;  // it == ee>>3
                ((uint4*)Bst)[sub * 8 + row * 2 + ((c0 >> 3) & 1)] = bv;
            }
            // fragments + 16 MFMA
            h8 bf[4];
#pragma unroll
            for (int ct = 0; ct < 4; ++ct) {
                h8 b;
#pragma unroll
                for (int jj2 = 0; jj2 < 8; ++jj2) {
                    int ee = (lane >> 4) * 8 + jj2;
                    int addr = ((ee >> 2) * 4 + ct) * 64 + ((ee & 3) ^ (lane >> 4)) * 16 +
                               (lane & 15);
                    b[jj2] = Bst[addr];
                }
                bf[ct] = b;
            }
#pragma unroll
            for (int mt = 0; mt < 4; ++mt) {
                int binr = mt * 16 + (lane & 15);
                int aoff = binr * 32 + (((lane >> 4) + (binr >> 1)) & 3) * 8;
                h8 a = *(const h8*)(Ast + aoff);
#pragma unroll
                for (int ct = 0; ct < 4; ++ct)
                    acc[mt * 4 + ct] = __builtin_amdgcn_mfma_f32_16x16x32_f16(
                        a, bf[ct], acc[mt * 4 + ct], 0, 0, 0);
            }
        }
        // writeback: frag-major p-layout, b64 writes (overwrites own staging)
#pragma unroll
        for (int t = 0; t < 16; ++t) {
            h2 lo = {(_Float16)acc[t][0], (_Float16)acc[t][1]};
            h2 hi = {(_Float16)acc[t][2], (_Float16)acc[t][3]};
            h2* dst = (h2*)(smem + w * RSH + t * 256 + (lane >> 4) * 64 + (lane & 15) * 4);
            dst[0] = lo;
            dst[1] = hi;
        }
        // dense row p = 4096 + c (xh is already relu'd fp16)
        smem[w * RSH + 4096 + lane] = xh[(size_t)n * 64 + lane];
    }

    // ---- phase 2: second GEMM, K-chunk for this wave (130 = 2*9 + 14*8)
    const int s0 = w * 8 + min(w, 2);
    const int s_end = s0 + 8 + (w < 2 ? 1 : 0);
    const int quad = lane >> 4;
    const _Float16* arow = smem + (lane & 15) * RSH;

    const uint4* Bp = (const uint4*)Wh;
    uint4 b0[4], b1[4];
#pragma unroll
    for (int t = 0; t < 4; ++t) {  // global prefetch (no LDS dep) before barrier
        b0[t] = Bp[((size_t)t * KSTEPS + s0) * 64 + lane];
        b1[t] = Bp[((size_t)t * KSTEPS + s0 + 1) * 64 + lane];
    }
    __syncthreads();
    f32x4 acc2[4] = {{0, 0, 0, 0}, {0, 0, 0, 0}, {0, 0, 0, 0}, {0, 0, 0, 0}};
    for (int s = s0; s < s_end; ++s) {
        uint4 bq[4];
#pragma unroll
        for (int t = 0; t < 4; ++t) {
            bq[t] = b0[t];
            b0[t] = b1[t];
            if (s + 2 < s_end) b1[t] = Bp[((size_t)t * KSTEPS + s + 2) * 64 + lane];
        }
        h8 a = *(const h8*)(arow + s * 32 + quad * 8);
#pragma unroll
        for (int t = 0; t < 4; ++t)
            acc2[t] = __builtin_amdgcn_mfma_f32_16x16x32_f16(a, __builtin_bit_cast(h8, bq[t]),
                                                             acc2[t], 0, 0, 0);
    }
    __syncthreads();  // moments dead -> reuse as reduce scratch (64 KB)
    f32x4* red = (f32x4*)smem;
#pragma unroll
    for (int t = 0; t < 4; ++t) red[(w * 4 + t) * 64 + lane] = acc2[t];
    __syncthreads();
    if (w < 4) {
        f32x4 s = {0, 0, 0, 0};
#pragma unroll
        for (int g = 0; g < 16; ++g) s += red[(g * 4 + w) * 64 + lane];
        const int co = w * 16 + (lane & 15);
#pragma unroll
        for (int i = 0; i < 4; ++i) {
            int nn = base + quad * 4 + i;
            if (nn < nNodes) {
                float res = s[i] + cb[co] + fb[co];
                if (MODE == 2) res += x32[(size_t)nn * 64 + co];
                out32[(size_t)nn * 64 + co] = res;
                if (MODE == 1) xh_out[(size_t)nn * 64 + co] = (_Float16)fmaxf(res, 0.f);
            }
        }
    }
}

// ---------------------------------------------------------------------------
// Layer 3 (CIN=64, COUT=2): direct per-edge form, f32 x (precision).
__global__ __launch_bounds__(1024, 4) void conv_last(
    const float* __restrict__ x, const float* __restrict__ cw3, const float* __restrict__ fw3,
    const float* __restrict__ cb3, const float* __restrict__ fb3,
    const int* __restrict__ offs, const uint4* __restrict__ csr_all,
    float* __restrict__ out, int nNodes) {
    constexpr int TM = 16;
    __shared__ float2 W2[4096];   // 32 KB
    __shared__ float2 FW2[64];    // 512 B
    const int tid = threadIdx.x;
    const int w = tid >> 6;
    const int lane = tid & 63;
    const int base = blockIdx.x * TM;
    const int n = base + w;

    {  // stage weights
        const float2* src = (const float2*)cw3;
        for (int d = tid; d < 4096; d += 1024) W2[d] = src[d];
        if (tid < 64) FW2[tid] = ((const float2*)fw3)[tid];
    }
    __syncthreads();

    float2 acc = make_float2(0.f, 0.f);
    if (n < nNodes) {
        const int e0 = offs[n], e1 = offs[n + 1];
        const int c = lane;
        for (int b = e0; b < e1; b += 4) {
            uint4 ca[4];
            float xv[4];
#pragma unroll
            for (int u = 0; u < 4; ++u) {
                int e = b + u;
                bool ok = e < e1;
                ca[u] = csr_all[ok ? e : e0];
                xv[u] = ok ? 1.f : 0.f;
            }
#pragma unroll
            for (int u = 0; u < 4; ++u) {
                int j = ca[u].x & 0x1FFFF;
                xv[u] *= fmaxf(x[j * 64 + c], 0.f);
            }
#pragma unroll
            for (int u = 0; u < 4; ++u) {
                int r0 = ((ca[u].x >> 17) & 3) << 1;
                int r1 = (((ca[u].x >> 19) & 3) << 1) + 1;
                int iv = (ca[u].x >> 21) & 7;
                h2 wh0 = __builtin_bit_cast(h2, ca[u].z);
                h2 wh1 = __builtin_bit_cast(h2, ca[u].w);
                float w00 = (float)wh0[0], w01 = (float)wh0[1];
                float w10 = (float)wh1[0], w11 = (float)wh1[1];
                int b00 = (r0 * 8 + iv) * 64 + c;
                int b10 = (r1 * 8 + iv) * 64 + c;
                float2 t00 = W2[b00], t01 = W2[b00 + 64];
                float2 t10 = W2[b10], t11 = W2[b10 + 64];
                float wsx = w00 * t00.x + w01 * t01.x + w10 * t10.x + w11 * t11.x;
                float wsy = w00 * t00.y + w01 * t01.y + w10 * t10.y + w11 * t11.y;
                acc.x += xv[u] * wsx;
                acc.y += xv[u] * wsy;
            }
        }
        // dense branch
        float xr = fmaxf(x[n * 64 + c], 0.f);
        float2 fwp = FW2[c];
        acc.x += xr * fwp.x;
        acc.y += xr * fwp.y;
    }
    // butterfly reduce over 64 lanes
#pragma unroll
    for (int d = 1; d < 64; d <<= 1) {
        acc.x += __shfl_xor(acc.x, d);
        acc.y += __shfl_xor(acc.y, d);
    }
    if (lane == 0 && n < nNodes) {
        out[n * 2 + 0] = (acc.x + cb3[0] + fb3[0]) * (1.f / 128.f);
        out[n * 2 + 1] = (acc.y + cb3[1] + fb3[1]) * (1.f / 128.f);
    }
}

// ---------------------------------------------------------------------------
// Layer 0 (CIN=4, no relu on input): direct per-edge form.
// Output: fp16 relu'd activations [lin(32) | conv(32)] for the MFMA layers.
__global__ __launch_bounds__(1024, 4) void conv0_direct(
    const float* __restrict__ x, const float* __restrict__ cw0, const float* __restrict__ fw0,
    const float* __restrict__ cb0, const float* __restrict__ fb0,
    const int* __restrict__ offs, const uint4* __restrict__ csr_all,
    _Float16* __restrict__ out, int nNodes) {
    constexpr int TM = 16;
    __shared__ float2 W0p[4096];  // 32 KB
    __shared__ float2 FW0p[64];   // [h*32+co] = (fw0[2h][co], fw0[2h+1][co])
    const int tid = threadIdx.x;
    const int w = tid >> 6;
    const int lane = tid & 63;
    const int base = blockIdx.x * TM;
    const int n = base + w;

    {  // stage W0 permuted
        for (int d = tid; d < 4096; d += 1024) {
            int co = d & 31;
            int h = (d >> 5) & 1;
            int bin = d >> 6;
            W0p[d] = make_float2(cw0[(bin * 4 + 2 * h) * 32 + co],
                                 cw0[(bin * 4 + 2 * h + 1) * 32 + co]);
        }
        if (tid < 64) {
            int co = tid & 31;
            int h = tid >> 5;
            FW0p[tid] = make_float2(fw0[(2 * h) * 32 + co], fw0[(2 * h + 1) * 32 + co]);
        }
    }
    __syncthreads();

    const int co = lane & 31;
    const int h = lane >> 5;
    float accC = 0.f, accL = 0.f;
    if (n < nNodes) {
        const int e0 = offs[n], e1 = offs[n + 1];
        for (int b = e0; b < e1; b += 4) {
            uint4 ca[4];
            float xc0[4], xc1[4];
#pragma unroll
            for (int u = 0; u < 4; ++u) {
                int e = b + u;
                bool ok = e < e1;
                ca[u] = csr_all[ok ? e : e0];
                xc0[u] = ok ? 1.f : 0.f;
            }
#pragma unroll
            for (int u = 0; u < 4; ++u) {
                int j = ca[u].x & 0x1FFFF;
                const float4 xj = *(const float4*)(x + j * 4);  // no relu (layer 0)
                float a = h ? xj.z : xj.x;
                float bb = h ? xj.w : xj.y;
                xc1[u] = xc0[u] * bb;
                xc0[u] = xc0[u] * a;
            }
#pragma unroll
            for (int u = 0; u < 4; ++u) {
                int r0 = ((ca[u].x >> 17) & 3) << 1;
                int r1 = (((ca[u].x >> 19) & 3) << 1) + 1;
                int iv = (ca[u].x >> 21) & 7;
                h2 wh0 = __builtin_bit_cast(h2, ca[u].z);
                h2 wh1 = __builtin_bit_cast(h2, ca[u].w);
                float w00 = (float)wh0[0], w01 = (float)wh0[1];
                float w10 = (float)wh1[0], w11 = (float)wh1[1];
                int i00 = ((r0 * 8 + iv) * 2 + h) * 32 + co;
                int i10 = ((r1 * 8 + iv) * 2 + h) * 32 + co;
                float2 t00 = W0p[i00], t01 = W0p[i00 + 64];
                float2 t10 = W0p[i10], t11 = W0p[i10 + 64];
                accC += w00 * (xc0[u] * t00.x + xc1[u] * t00.y);
                accC += w01 * (xc0[u] * t01.x + xc1[u] * t01.y);
                accC += w10 * (xc0[u] * t10.x + xc1[u] * t10.y);
                accC += w11 * (xc0[u] * t11.x + xc1[u] * t11.y);
            }
        }
        // lin branch (no relu on input)
        const float4 xn = *(const float4*)(x + n * 4);
        float a = h ? xn.z : xn.x;
        float bb = h ? xn.w : xn.y;
        float2 fwp = FW0p[h * 32 + co];
        accL = a * fwp.x + bb * fwp.y;
    }
    accC += __shfl_xor(accC, 32);
    accL += __shfl_xor(accL, 32);
    if (lane < 32 && n < nNodes) {
        out[n * 64 + co] = (_Float16)fmaxf(accL + fb0[co], 0.f);
        out[n * 64 + 32 + co] = (_Float16)fmaxf(accC + cb0[co], 0.f);
    }
}

extern "C" void kernel_launch(void* const* d_in, const int* in_sizes, int n_in,
                              void* d_out, int out_size, void* d_ws, size_t ws_size,
                              hipStream_t stream) {
    const float* pos = (const float*)d_in[0];
    const float* feat = (const float*)d_in[1];
    const int* ei = (const int*)d_in[2];
    const int* ej = (const int*)d_in[3];
    const float* cw0 = (const float*)d_in[4];
    const float* cb0 = (const float*)d_in[5];
    const float* fw0 = (const float*)d_in[6];
    const float* fb0 = (const float*)d_in[7];
    const float* cw1 = (const float*)d_in[8];
    const float* cb1 = (const float*)d_in[9];
    const float* fw1 = (const float*)d_in[10];
    const float* fb1 = (const float*)d_in[11];
    const float* cw2 = (const float*)d_in[12];
    const float* cb2 = (const float*)d_in[13];
    const float* fw2 = (const float*)d_in[14];
    const float* fb2 = (const float*)d_in[15];
    const float* cw3 = (const float*)d_in[16];
    const float* cb3 = (const float*)d_in[17];
    const float* fw3 = (const float*)d_in[18];
    const float* fb3 = (const float*)d_in[19];
    float* outp = (float*)d_out;

    const int N = in_sizes[0] / 2;
    const int E = in_sizes[2];

    char* wsp = (char*)d_ws;
    size_t off = 0;
    auto alloc = [&](size_t bytes) -> void* {
        void* p = wsp + off;
        off = (off + bytes + 255) & ~(size_t)255;
        return p;
    };
    int* counts = (int*)alloc((size_t)N * 4);
    int* offs = (int*)alloc((size_t)(N + 1) * 4);
    int* cursor = (int*)alloc((size_t)N * 4);
    uint4* csr_all = (uint4*)alloc((size_t)E * 16);
    float* ansA = (float*)alloc((size_t)N * 64 * 4);
    float* ansB = (float*)alloc((size_t)N * 64 * 4);
    _Float16* xhB = (_Float16*)alloc((size_t)N * 64 * 2);
    _Float16* Wh1 = (_Float16*)alloc((size_t)4 * 130 * 512 * 2);
    _Float16* Wh2 = (_Float16*)alloc((size_t)4 * 130 * 512 * 2);
    // xh0 (conv0 out, conv64<1> in) aliases ansA (written later by conv64<2>):
    // lifetimes are disjoint.
    _Float16* xh0 = (_Float16*)ansA;
    (void)ws_size;
    (void)n_in;
    (void)out_size;

    const int BIG_LDS = 16 * 4168 * 2;  // 133376 B
    hipFuncSetAttribute((const void*)&conv64_mfma<1>,
                        hipFuncAttributeMaxDynamicSharedMemorySize, BIG_LDS);
    hipFuncSetAttribute((const void*)&conv64_mfma<2>,
                        hipFuncAttributeMaxDynamicSharedMemorySize, BIG_LDS);

    zero_ints<<<dim3((N + 255) / 256), dim3(256), 0, stream>>>(counts, N);
    const int RT = 4 * 130 * 512;
    repack_wh<<<dim3((RT + 255) / 256), dim3(256), 0, stream>>>(cw1, fw1, Wh1);
    repack_wh<<<dim3((RT + 255) / 256), dim3(256), 0, stream>>>(cw2, fw2, Wh2);
    edge_hist<<<dim3((E + 255) / 256), dim3(256), 0, stream>>>(ei, ej, counts, E);
    scan_kernel<<<dim3(1), dim3(1024), 0, stream>>>(counts, offs, cursor, N);
    edge_scatter<<<dim3((E + 255) / 256), dim3(256), 0, stream>>>(ei, ej, pos, cursor, csr_all, E);

    const int nb = (N + 15) / 16;
    conv0_direct<<<dim3(nb), dim3(1024), 0, stream>>>(
        feat, cw0, fw0, cb0, fb0, offs, csr_all, xh0, N);
    conv64_mfma<1><<<dim3(nb), dim3(1024), BIG_LDS, stream>>>(
        xh0, (const float*)nullptr, Wh1, cb1, fb1, offs, csr_all, ansB, xhB, N);
    conv64_mfma<2><<<dim3(nb), dim3(1024), BIG_LDS, stream>>>(
        xhB, ansB, Wh2, cb2, fb2, offs, csr_all, ansA, (_Float16*)nullptr, N);
    conv_last<<<dim3(nb), dim3(1024), 0, stream>>>(
        ansA, cw3, fw3, cb3, fb3, offs, csr_all, outp, N);
}

// Round 5
// 856.816 us; speedup vs baseline: 2.5698x; 1.0683x over previous
//
#include <hip/hip_runtime.h>
#include <math.h>

typedef _Float16 h8 __attribute__((ext_vector_type(8)));
typedef _Float16 h2 __attribute__((ext_vector_type(2)));
typedef float f32x4 __attribute__((ext_vector_type(4)));

__device__ __forceinline__ float clampf(float x, float lo, float hi) {
    return fminf(fmaxf(x, lo), hi);
}

__global__ void zero_ints(int* __restrict__ p, int n) {
    int i = blockIdx.x * 256 + threadIdx.x;
    if (i < n) p[i] = 0;
}

// fp16 B repack for CIN=64 layers, frag-major physical k' (= p) layout:
// p < 4096:  tile = p>>8 (mt = tile>>2, ct = tile&3); g = (p>>6)&3;
//            m = (p>>2)&15; i = p&3; bin = mt*16+g*4+i; c = ct*16+m -> cw[bin][c]
// p >= 4096: fw row c = p-4096   (4096..4159; 130 K-steps * 32 = 4160 exactly)
// Wh half idx = ((t*130 + s)*512) + l*8 + j8 ; p = s*32 + (l>>4)*8 + j8
__global__ void repack_wh(const float* __restrict__ cw, const float* __restrict__ fw,
                          _Float16* __restrict__ Wh) {
    int idx = blockIdx.x * 256 + threadIdx.x;
    int total = 4 * 130 * 512;
    if (idx >= total) return;
    int j8 = idx & 7;
    int l = (idx >> 3) & 63;
    int rest = idx >> 9;
    int s = rest % 130;
    int t = rest / 130;
    int p = s * 32 + ((l >> 4) * 8) + j8;
    int co = t * 16 + (l & 15);
    float v = 0.f;
    if (p < 4096) {
        int tile = p >> 8;
        int g = (p >> 6) & 3;
        int m = (p >> 2) & 15;
        int i = p & 3;
        int mt = tile >> 2;
        int ct = tile & 3;
        int bin = mt * 16 + g * 4 + i;
        int c = ct * 16 + m;
        v = cw[(bin * 64 + c) * 64 + co];
    } else if (p < 4160) {
        v = fw[(p - 4096) * 64 + co];
    }
    Wh[idx] = (_Float16)v;
}

// Same p-layout, COUT=2 (layer 3). Wh3 idx = (s*512) + l*8 + j8, t = 0 only;
// co = l&15 (valid for co<2, else 0).
__global__ void repack_wh3(const float* __restrict__ cw, const float* __restrict__ fw,
                           _Float16* __restrict__ Wh) {
    int idx = blockIdx.x * 256 + threadIdx.x;
    int total = 130 * 512;
    if (idx >= total) return;
    int j8 = idx & 7;
    int l = (idx >> 3) & 63;
    int s = idx >> 9;
    int p = s * 32 + ((l >> 4) * 8) + j8;
    int co = l & 15;
    float v = 0.f;
    if (co < 2) {
        if (p < 4096) {
            int tile = p >> 8;
            int g = (p >> 6) & 3;
            int m = (p >> 2) & 15;
            int i = p & 3;
            int mt = tile >> 2;
            int ct = tile & 3;
            int bin = mt * 16 + g * 4 + i;
            int c = ct * 16 + m;
            v = cw[(bin * 64 + c) * 2 + co];
        } else if (p < 4160) {
            v = fw[(p - 4096) * 2 + co];
        }
    }
    Wh[idx] = (_Float16)v;
}

// Layer-0 combined weight repack. k-layout: p<256: bin = p&63, c = p>>6 (Cin=4);
// p in [256,260): dense row c' = p-256 (raw x, lin branch); p>=260: pad 0.
// cols co<32 = lin (fw0 rows only), co>=32 = conv (cw0 only).
// W0h idx = ((t*9 + s)*512) + l*8 + j8 ; p = s*32 + (l>>4)*8 + j8; co = t*16+(l&15)
__global__ void repack_w0h(const float* __restrict__ cw0, const float* __restrict__ fw0,
                           _Float16* __restrict__ Wh) {
    int idx = blockIdx.x * 256 + threadIdx.x;
    int total = 4 * 9 * 512;
    if (idx >= total) return;
    int j8 = idx & 7;
    int l = (idx >> 3) & 63;
    int rest = idx >> 9;
    int s = rest % 9;
    int t = rest / 9;
    int p = s * 32 + ((l >> 4) * 8) + j8;
    int co = t * 16 + (l & 15);
    float v = 0.f;
    if (p < 256) {
        int bin = p & 63;
        int c = p >> 6;
        if (co >= 32) v = cw0[(bin * 4 + c) * 32 + (co - 32)];
    } else if (p < 260) {
        int c = p - 256;
        if (co < 32) v = fw0[c * 32 + co];
    }
    Wh[idx] = (_Float16)v;
}

__global__ void edge_hist(const int* __restrict__ ei, const int* __restrict__ ej,
                          int* __restrict__ counts, int E) {
    int e = blockIdx.x * 256 + threadIdx.x;
    if (e >= E) return;
    int i = ei[e], j = ej[e];
    if (i != j) atomicAdd(&counts[i], 1);
}

__global__ __launch_bounds__(1024) void scan_kernel(const int* __restrict__ counts,
                                                    int* __restrict__ offs,
                                                    int* __restrict__ cursor, int N) {
    __shared__ int sums[1024];
    const int t = threadIdx.x;
    const int per = (N + 1023) / 1024;
    const int lo = t * per;
    const int hi = min(lo + per, N);
    int s = 0;
    for (int i = lo; i < hi; ++i) s += counts[i];
    sums[t] = s;
    __syncthreads();
    for (int d = 1; d < 1024; d <<= 1) {
        int v = (t >= d) ? sums[t - d] : 0;
        __syncthreads();
        sums[t] += v;
        __syncthreads();
    }
    int run = (t > 0) ? sums[t - 1] : 0;
    for (int i = lo; i < hi; ++i) {
        offs[i] = run;
        cursor[i] = run;
        run += counts[i];
    }
    if (t == 1023) offs[N] = sums[1023];
}

// csr_all[e] = uint4:
//   .x = j[0:17) | r0>>1 [17:19) | r1>>1 [19:21) | iv [21:24)
//   .y = unused (legacy)
//   .z = fp16x2 {wu0*gv, wu0*fv}   (even u-row r0 taps at iv, iv+1)
//   .w = fp16x2 {wu1*gv, wu1*fv}   (odd  u-row r1 taps at iv, iv+1)
__global__ void edge_scatter(const int* __restrict__ ei, const int* __restrict__ ej,
                             const float* __restrict__ pos, int* __restrict__ cursor,
                             uint4* __restrict__ csr_all, int E) {
    int e = blockIdx.x * 256 + threadIdx.x;
    if (e >= E) return;
    int i = ei[e], j = ej[e];
    if (i == j) return;
    float dx = clampf(pos[i * 2 + 0] - pos[j * 2 + 0], -1.f, 1.f);
    float dy = clampf(pos[i * 2 + 1] - pos[j * 2 + 1], -1.f, 1.f);
    float r = sqrtf(dx * dx + dy * dy + 1e-12f);
    float u = clampf(2.f * r - 1.f, -1.f, 1.f);
    float v = atan2f(dy, dx) * 0.3183098861837907f;  // / pi
    float tu = (u + 1.f) * 3.5f;
    float tv = (v + 1.f) * 3.5f;
    int iu = min(6, max(0, (int)floorf(tu)));
    int iv = min(6, max(0, (int)floorf(tv)));
    float fu = clampf(tu - (float)iu, 0.f, 1.f);
    float fv = clampf(tv - (float)iv, 0.f, 1.f);
    bool even = (iu & 1) == 0;
    int rowi0 = even ? iu : iu + 1;  // even u-row
    int rowi1 = even ? iu + 1 : iu;  // odd u-row
    float wu0 = even ? (1.f - fu) : fu;
    float wu1 = even ? fu : (1.f - fu);
    float gv = 1.f - fv;
    unsigned a0 = (unsigned)__builtin_bit_cast(unsigned short, (_Float16)(wu0 * gv)) |
                  ((unsigned)__builtin_bit_cast(unsigned short, (_Float16)(wu0 * fv)) << 16);
    unsigned a1 = (unsigned)__builtin_bit_cast(unsigned short, (_Float16)(wu1 * gv)) |
                  ((unsigned)__builtin_bit_cast(unsigned short, (_Float16)(wu1 * fv)) << 16);
    int p = atomicAdd(&cursor[i], 1);
    csr_all[p] = make_uint4(
        (unsigned)j | ((unsigned)(rowi0 >> 1) << 17) | ((unsigned)(rowi1 >> 1) << 19) |
            ((unsigned)iv << 21),
        0u, a0, a1);
}

// ---------------------------------------------------------------------------
// Shared phase 1 (verified round 4): per-wave 32-edge K-tiles.
//   A = basis [64 bins x 32 e] fp16, zeroed + 4-tap sparse scatter, swizzled.
//   B = gathered xh rows [32 e x 64 c] fp16, subtiled+XOR (b128 writes).
//   acc[16] = mom [64 bins x 64 c] f32 (16 MFMA per tile).
__device__ __forceinline__ void mom_phase1_64(
    const _Float16* __restrict__ xh, const uint4* __restrict__ csr_all,
    _Float16* Ast, _Float16* Bst, int e0, int e1, int lane, f32x4* acc) {
    const int half = lane >> 5;
    const int el = lane & 31;
    for (int bs = e0; bs < e1; bs += 32) {
        {  // zero A (4 KB)
            uint4 z4 = make_uint4(0, 0, 0, 0);
#pragma unroll
            for (int zz = 0; zz < 4; ++zz) ((uint4*)Ast)[zz * 64 + lane] = z4;
        }
        int e = bs + el;
        bool ok = e < e1;
        uint4 ca = csr_all[ok ? e : e0];
        int jme = ok ? (int)(ca.x & 0x1FFFF) : -1;
        {
            int iv = (ca.x >> 21) & 7;
            int rowi = half ? (int)((((ca.x >> 19) & 3) << 1) + 1)
                            : (int)(((ca.x >> 17) & 3) << 1);
            h2 wts = __builtin_bit_cast(h2, half ? ca.w : ca.z);
            if (ok) {
                int bin0 = rowi * 8 + iv;
                int bin1 = bin0 + 1;
                int a0 = bin0 * 32 + (((el >> 3) + (bin0 >> 1)) & 3) * 8 + (el & 7);
                int a1 = bin1 * 32 + (((el >> 3) + (bin1 >> 1)) & 3) * 8 + (el & 7);
                Ast[a0] = wts[0];
                Ast[a1] = wts[1];
            }
        }
#pragma unroll
        for (int it = 0; it < 4; ++it) {
            int ee = it * 8 + (lane >> 3);
            int jj = __shfl(jme, ee);
            int c0 = (lane & 7) * 8;
            uint4 bv = make_uint4(0, 0, 0, 0);
            if (jj >= 0) bv = *(const uint4*)(xh + (size_t)jj * 64 + c0);
            int sub = (ee >> 2) * 4 + (c0 >> 4);
            int row = (ee & 3) ^ it;
            ((uint4*)Bst)[sub * 8 + row * 2 + ((c0 >> 3) & 1)] = bv;
        }
        h8 bf[4];
#pragma unroll
        for (int ct = 0; ct < 4; ++ct) {
            h8 b;
#pragma unroll
            for (int jj2 = 0; jj2 < 8; ++jj2) {
                int ee = (lane >> 4) * 8 + jj2;
                int addr = ((ee >> 2) * 4 + ct) * 64 + ((ee & 3) ^ (lane >> 4)) * 16 +
                           (lane & 15);
                b[jj2] = Bst[addr];
            }
            bf[ct] = b;
        }
#pragma unroll
        for (int mt = 0; mt < 4; ++mt) {
            int binr = mt * 16 + (lane & 15);
            int aoff = binr * 32 + (((lane >> 4) + (binr >> 1)) & 3) * 8;
            h8 a = *(const h8*)(Ast + aoff);
#pragma unroll
            for (int ct = 0; ct < 4; ++ct)
                acc[mt * 4 + ct] = __builtin_amdgcn_mfma_f32_16x16x32_f16(
                    a, bf[ct], acc[mt * 4 + ct], 0, 0, 0);
        }
    }
}

// Writeback acc[16] -> frag-major p-layout (p = t*256 + g*64 + m*4 + i), fp16.
__device__ __forceinline__ void mom_writeback_64(const f32x4* acc, _Float16* momrow,
                                                 int lane) {
#pragma unroll
    for (int t = 0; t < 16; ++t) {
        h2 lo = {(_Float16)acc[t][0], (_Float16)acc[t][1]};
        h2 hi = {(_Float16)acc[t][2], (_Float16)acc[t][3]};
        h2* dst = (h2*)(momrow + t * 256 + (lane >> 4) * 64 + (lane & 15) * 4);
        dst[0] = lo;
        dst[1] = hi;
    }
}

// ---------------------------------------------------------------------------
// Layers 1..2 (CIN=64, COUT=64). RSH 4168->4184: row stride 8368 B == 48 B mod
// 128 B -> phase-2 ds_read_b128 bank phase m*12 mod 32 (period 8) = 2-way
// (free), was 16 B mod 128 = 8-way (the 12.2M SQ_LDS_BANK_CONFLICT of r4).
// MODE 1: out32 = gemm+cb+fb (residual src), xh_out = fp16(relu(out32))
// MODE 2: res += x32 (residual); only xh_out written (f32 out unused).
template <int MODE>
__global__ __launch_bounds__(1024, 4) void conv64_mfma(
    const _Float16* __restrict__ xh, const float* __restrict__ x32,
    const _Float16* __restrict__ Wh,
    const float* __restrict__ cb, const float* __restrict__ fb,
    const int* __restrict__ offs, const uint4* __restrict__ csr_all,
    float* __restrict__ out32, _Float16* __restrict__ xh_out, int nNodes) {
    constexpr int TM = 16;
    constexpr int KSTEPS = 130;
    constexpr int RSH = 4184;            // halfs per node row (8368 B)
    extern __shared__ _Float16 smem[];   // 16 * 4184 * 2 = 133888 B
    const int tid = threadIdx.x;
    const int w = tid >> 6;
    const int lane = tid & 63;
    const int base = blockIdx.x * TM;
    const int n = base + w;

    _Float16* Ast = smem + w * RSH;      // 2048 halfs staging (overlays mom row)
    _Float16* Bst = Ast + 2048;          // 2048 halfs

    f32x4 acc[16] = {{0, 0, 0, 0}, {0, 0, 0, 0}, {0, 0, 0, 0}, {0, 0, 0, 0},
                     {0, 0, 0, 0}, {0, 0, 0, 0}, {0, 0, 0, 0}, {0, 0, 0, 0},
                     {0, 0, 0, 0}, {0, 0, 0, 0}, {0, 0, 0, 0}, {0, 0, 0, 0},
                     {0, 0, 0, 0}, {0, 0, 0, 0}, {0, 0, 0, 0}, {0, 0, 0, 0}};

    if (n < nNodes) {
        mom_phase1_64(xh, csr_all, Ast, Bst, offs[n], offs[n + 1], lane, acc);
        mom_writeback_64(acc, smem + w * RSH, lane);
        smem[w * RSH + 4096 + lane] = xh[(size_t)n * 64 + lane];  // dense row
    }

    // ---- phase 2: K-chunk for this wave (130 = 2*9 + 14*8)
    const int s0 = w * 8 + min(w, 2);
    const int s_end = s0 + 8 + (w < 2 ? 1 : 0);
    const int quad = lane >> 4;
    const _Float16* arow = smem + (lane & 15) * RSH;

    const uint4* Bp = (const uint4*)Wh;
    uint4 b0[4], b1[4];
#pragma unroll
    for (int t = 0; t < 4; ++t) {  // global prefetch (no LDS dep) before barrier
        b0[t] = Bp[((size_t)t * KSTEPS + s0) * 64 + lane];
        b1[t] = Bp[((size_t)t * KSTEPS + s0 + 1) * 64 + lane];
    }
    __syncthreads();
    f32x4 acc2[4] = {{0, 0, 0, 0}, {0, 0, 0, 0}, {0, 0, 0, 0}, {0, 0, 0, 0}};
    for (int s = s0; s < s_end; ++s) {
        uint4 bq[4];
#pragma unroll
        for (int t = 0; t < 4; ++t) {
            bq[t] = b0[t];
            b0[t] = b1[t];
            if (s + 2 < s_end) b1[t] = Bp[((size_t)t * KSTEPS + s + 2) * 64 + lane];
        }
        h8 a = *(const h8*)(arow + s * 32 + quad * 8);
#pragma unroll
        for (int t = 0; t < 4; ++t)
            acc2[t] = __builtin_amdgcn_mfma_f32_16x16x32_f16(a, __builtin_bit_cast(h8, bq[t]),
                                                             acc2[t], 0, 0, 0);
    }
    __syncthreads();  // moments dead -> reuse as reduce scratch (64 KB)
    f32x4* red = (f32x4*)smem;
#pragma unroll
    for (int t = 0; t < 4; ++t) red[(w * 4 + t) * 64 + lane] = acc2[t];
    __syncthreads();
    if (w < 4) {
        f32x4 s = {0, 0, 0, 0};
#pragma unroll
        for (int g = 0; g < 16; ++g) s += red[(g * 4 + w) * 64 + lane];
        const int co = w * 16 + (lane & 15);
#pragma unroll
        for (int i = 0; i < 4; ++i) {
            int nn = base + quad * 4 + i;
            if (nn < nNodes) {
                float res = s[i] + cb[co] + fb[co];
                if (MODE == 2) res += x32[(size_t)nn * 64 + co];
                if (MODE == 1) out32[(size_t)nn * 64 + co] = res;
                xh_out[(size_t)nn * 64 + co] = (_Float16)fmaxf(res, 0.f);
            }
        }
    }
}

// ---------------------------------------------------------------------------
// Layer 3 (CIN=64, COUT=2): same phase 1 as conv64; phase 2 = 1 MFMA t-tile
// (cols 0..1 real). out = (gemm + cb3 + fb3) / 128.
__global__ __launch_bounds__(1024, 4) void conv_last_mfma(
    const _Float16* __restrict__ xh, const _Float16* __restrict__ Wh3,
    const float* __restrict__ cb3, const float* __restrict__ fb3,
    const int* __restrict__ offs, const uint4* __restrict__ csr_all,
    float* __restrict__ out, int nNodes) {
    constexpr int TM = 16;
    constexpr int RSH = 4184;
    extern __shared__ _Float16 smem[];   // 133888 B
    const int tid = threadIdx.x;
    const int w = tid >> 6;
    const int lane = tid & 63;
    const int base = blockIdx.x * TM;
    const int n = base + w;

    _Float16* Ast = smem + w * RSH;
    _Float16* Bst = Ast + 2048;

    f32x4 acc[16] = {{0, 0, 0, 0}, {0, 0, 0, 0}, {0, 0, 0, 0}, {0, 0, 0, 0},
                     {0, 0, 0, 0}, {0, 0, 0, 0}, {0, 0, 0, 0}, {0, 0, 0, 0},
                     {0, 0, 0, 0}, {0, 0, 0, 0}, {0, 0, 0, 0}, {0, 0, 0, 0},
                     {0, 0, 0, 0}, {0, 0, 0, 0}, {0, 0, 0, 0}, {0, 0, 0, 0}};

    if (n < nNodes) {
        mom_phase1_64(xh, csr_all, Ast, Bst, offs[n], offs[n + 1], lane, acc);
        mom_writeback_64(acc, smem + w * RSH, lane);
        smem[w * RSH + 4096 + lane] = xh[(size_t)n * 64 + lane];  // dense (relu'd)
    }

    const int s0 = w * 8 + min(w, 2);
    const int s_end = s0 + 8 + (w < 2 ? 1 : 0);
    const int quad = lane >> 4;
    const _Float16* arow = smem + (lane & 15) * RSH;
    const uint4* Bp = (const uint4*)Wh3;

    __syncthreads();
    f32x4 acc2 = {0, 0, 0, 0};
    for (int s = s0; s < s_end; ++s) {
        uint4 bq = Bp[(size_t)s * 64 + lane];
        h8 a = *(const h8*)(arow + s * 32 + quad * 8);
        acc2 = __builtin_amdgcn_mfma_f32_16x16x32_f16(a, __builtin_bit_cast(h8, bq),
                                                      acc2, 0, 0, 0);
    }
    __syncthreads();
    f32x4* red = (f32x4*)smem;
    red[w * 64 + lane] = acc2;
    __syncthreads();
    if (w == 0) {
        f32x4 s = {0, 0, 0, 0};
#pragma unroll
        for (int g = 0; g < 16; ++g) s += red[g * 64 + lane];
        const int co = lane & 15;
        if (co < 2) {
#pragma unroll
            for (int i = 0; i < 4; ++i) {
                int nn = base + quad * 4 + i;
                if (nn < nNodes)
                    out[nn * 2 + co] = (s[i] + cb3[co] + fb3[co]) * (1.f / 128.f);
            }
        }
    }
}

// ---------------------------------------------------------------------------
// Layer 0 (CIN=4, raw f32 x, no relu): shrunk moment-GEMM.
// Phase 1: A tile identical to conv64; B tile [32 e][16 c] (c 0..3 real,
// 4..15 zero) written as 2 b128 per edge-lane; 1 ct -> 4 MFMA per tile.
// mom k-layout: p = bin + 64*c (p<256); p in [256,260) = dense raw x;
// [260,288) zero pad. RSH0 = 296 halfs (592 B == 80 mod 128 -> 2-way reads).
// Phase 2: KSTEPS=9, 4 t-tiles (cols: 0..31 lin | 32..63 conv).
// Epilogue: xh_out = fp16(relu(gemm + bias)).
__global__ __launch_bounds__(1024, 4) void conv0_mfma(
    const float* __restrict__ xf, const _Float16* __restrict__ W0h,
    const float* __restrict__ cb0, const float* __restrict__ fb0,
    const int* __restrict__ offs, const uint4* __restrict__ csr_all,
    _Float16* __restrict__ xh_out, int nNodes) {
    constexpr int TM = 16;
    constexpr int RSH0 = 296;
    constexpr int MOMSZ = 16 * RSH0;     // 4736 halfs
    extern __shared__ _Float16 smem[];   // (4736 + 16*2560)*2 = 91392 B
    const int tid = threadIdx.x;
    const int w = tid >> 6;
    const int lane = tid & 63;
    const int base = blockIdx.x * TM;
    const int n = base + w;

    _Float16* Ast = smem + MOMSZ + w * 2560;
    _Float16* Bst = Ast + 2048;
    _Float16* momrow = smem + w * RSH0;

    f32x4 acc[4] = {{0, 0, 0, 0}, {0, 0, 0, 0}, {0, 0, 0, 0}, {0, 0, 0, 0}};

    if (n < nNodes) {
        const int e0 = offs[n], e1 = offs[n + 1];
        const int half = lane >> 5;
        const int el = lane & 31;
        for (int bs = e0; bs < e1; bs += 32) {
            {  // zero A
                uint4 z4 = make_uint4(0, 0, 0, 0);
#pragma unroll
                for (int zz = 0; zz < 4; ++zz) ((uint4*)Ast)[zz * 64 + lane] = z4;
            }
            int e = bs + el;
            bool ok = e < e1;
            uint4 ca = csr_all[ok ? e : e0];
            int jme = ok ? (int)(ca.x & 0x1FFFF) : -1;
            {
                int iv = (ca.x >> 21) & 7;
                int rowi = half ? (int)((((ca.x >> 19) & 3) << 1) + 1)
                                : (int)(((ca.x >> 17) & 3) << 1);
                h2 wts = __builtin_bit_cast(h2, half ? ca.w : ca.z);
                if (ok) {
                    int bin0 = rowi * 8 + iv;
                    int bin1 = bin0 + 1;
                    int a0 = bin0 * 32 + (((el >> 3) + (bin0 >> 1)) & 3) * 8 + (el & 7);
                    int a1 = bin1 * 32 + (((el >> 3) + (bin1 >> 1)) & 3) * 8 + (el & 7);
                    Ast[a0] = wts[0];
                    Ast[a1] = wts[1];
                }
            }
            // B: one edge per half-0 lane; 4 real cols + 12 zeros, no XOR.
            if (half == 0) {
                float4 xj = make_float4(0.f, 0.f, 0.f, 0.f);
                if (jme >= 0) xj = *(const float4*)(xf + (size_t)jme * 4);
                h2 d0 = {(_Float16)xj.x, (_Float16)xj.y};
                h2 d1 = {(_Float16)xj.z, (_Float16)xj.w};
                uint4 bv = make_uint4(__builtin_bit_cast(unsigned, d0),
                                      __builtin_bit_cast(unsigned, d1), 0u, 0u);
                uint4* dst = (uint4*)Bst + (el >> 2) * 8 + (el & 3) * 2;
                dst[0] = bv;
                dst[1] = make_uint4(0, 0, 0, 0);
            }
            // B frag (subtiled, no XOR)
            h8 b;
#pragma unroll
            for (int jj2 = 0; jj2 < 8; ++jj2) {
                int ee = (lane >> 4) * 8 + jj2;
                b[jj2] = Bst[(ee >> 2) * 64 + (ee & 3) * 16 + (lane & 15)];
            }
#pragma unroll
            for (int mt = 0; mt < 4; ++mt) {
                int binr = mt * 16 + (lane & 15);
                int aoff = binr * 32 + (((lane >> 4) + (binr >> 1)) & 3) * 8;
                h8 a = *(const h8*)(Ast + aoff);
                acc[mt] = __builtin_amdgcn_mfma_f32_16x16x32_f16(a, b, acc[mt], 0, 0, 0);
            }
        }
        // writeback: p = bin + 64*c, only c = lane&15 < 4 valid
        if ((lane & 15) < 4) {
#pragma unroll
            for (int mt = 0; mt < 4; ++mt) {
                _Float16* dst = momrow + mt * 16 + (lane >> 4) * 4 + 64 * (lane & 15);
                ((h2*)dst)[0] = h2{(_Float16)acc[mt][0], (_Float16)acc[mt][1]};
                ((h2*)dst)[1] = h2{(_Float16)acc[mt][2], (_Float16)acc[mt][3]};
            }
        }
        if (lane < 7) {  // zero pad p in [260, 288)
            h2 z = {(_Float16)0.f, (_Float16)0.f};
            h2* zp = (h2*)(momrow + 260 + lane * 4);
            zp[0] = z;
            zp[1] = z;
        }
        if (lane < 4) momrow[256 + lane] = (_Float16)xf[(size_t)n * 4 + lane];  // dense raw
    }

    // phase 2: 9 K-steps over 16 waves (waves 9..15 idle)
    const int quad = lane >> 4;
    const _Float16* arow = smem + (lane & 15) * RSH0;
    const uint4* Bp = (const uint4*)W0h;
    __syncthreads();
    f32x4 acc2[4] = {{0, 0, 0, 0}, {0, 0, 0, 0}, {0, 0, 0, 0}, {0, 0, 0, 0}};
    const int s0 = min(w, 9), s_end = min(w + 1, 9);
    for (int s = s0; s < s_end; ++s) {
        uint4 bq[4];
#pragma unroll
        for (int t = 0; t < 4; ++t) bq[t] = Bp[((size_t)t * 9 + s) * 64 + lane];
        h8 a = *(const h8*)(arow + s * 32 + quad * 8);
#pragma unroll
        for (int t = 0; t < 4; ++t)
            acc2[t] = __builtin_amdgcn_mfma_f32_16x16x32_f16(a, __builtin_bit_cast(h8, bq[t]),
                                                             acc2[t], 0, 0, 0);
    }
    __syncthreads();
    f32x4* red = (f32x4*)(smem + MOMSZ);  // overlays dead staging
#pragma unroll
    for (int t = 0; t < 4; ++t) red[(w * 4 + t) * 64 + lane] = acc2[t];
    __syncthreads();
    if (w < 4) {
        f32x4 s = {0, 0, 0, 0};
#pragma unroll
        for (int g = 0; g < 16; ++g) s += red[(g * 4 + w) * 64 + lane];
        const int co = w * 16 + (lane & 15);
        const float bias = (co < 32) ? fb0[co] : cb0[co - 32];
#pragma unroll
        for (int i = 0; i < 4; ++i) {
            int nn = base + quad * 4 + i;
            if (nn < nNodes)
                xh_out[(size_t)nn * 64 + co] = (_Float16)fmaxf(s[i] + bias, 0.f);
        }
    }
}

extern "C" void kernel_launch(void* const* d_in, const int* in_sizes, int n_in,
                              void* d_out, int out_size, void* d_ws, size_t ws_size,
                              hipStream_t stream) {
    const float* pos = (const float*)d_in[0];
    const float* feat = (const float*)d_in[1];
    const int* ei = (const int*)d_in[2];
    const int* ej = (const int*)d_in[3];
    const float* cw0 = (const float*)d_in[4];
    const float* cb0 = (const float*)d_in[5];
    const float* fw0 = (const float*)d_in[6];
    const float* fb0 = (const float*)d_in[7];
    const float* cw1 = (const float*)d_in[8];
    const float* cb1 = (const float*)d_in[9];
    const float* fw1 = (const float*)d_in[10];
    const float* fb1 = (const float*)d_in[11];
    const float* cw2 = (const float*)d_in[12];
    const float* cb2 = (const float*)d_in[13];
    const float* fw2 = (const float*)d_in[14];
    const float* fb2 = (const float*)d_in[15];
    const float* cw3 = (const float*)d_in[16];
    const float* cb3 = (const float*)d_in[17];
    const float* fw3 = (const float*)d_in[18];
    const float* fb3 = (const float*)d_in[19];
    float* outp = (float*)d_out;

    const int N = in_sizes[0] / 2;
    const int E = in_sizes[2];

    char* wsp = (char*)d_ws;
    size_t off = 0;
    auto alloc = [&](size_t bytes) -> void* {
        void* p = wsp + off;
        off = (off + bytes + 255) & ~(size_t)255;
        return p;
    };
    int* counts = (int*)alloc((size_t)N * 4);
    int* offs = (int*)alloc((size_t)(N + 1) * 4);
    int* cursor = (int*)alloc((size_t)N * 4);
    uint4* csr_all = (uint4*)alloc((size_t)E * 16);
    float* ansB = (float*)alloc((size_t)N * 64 * 4);      // layer-1 f32 (residual)
    _Float16* xh0 = (_Float16*)alloc((size_t)N * 64 * 2);  // conv0 out (relu fp16)
    _Float16* xhB = (_Float16*)alloc((size_t)N * 64 * 2);  // layer-1 relu fp16
    _Float16* xhC = (_Float16*)alloc((size_t)N * 64 * 2);  // layer-2 relu fp16
    _Float16* Wh1 = (_Float16*)alloc((size_t)4 * 130 * 512 * 2);
    _Float16* Wh2 = (_Float16*)alloc((size_t)4 * 130 * 512 * 2);
    _Float16* Wh3 = (_Float16*)alloc((size_t)130 * 512 * 2);
    _Float16* W0h = (_Float16*)alloc((size_t)4 * 9 * 512 * 2);
    (void)ws_size;
    (void)n_in;
    (void)out_size;

    const int BIG_LDS = 16 * 4184 * 2;             // 133888 B
    const int LDS0 = (16 * 296 + 16 * 2560) * 2;   // 91392 B
    hipFuncSetAttribute((const void*)&conv64_mfma<1>,
                        hipFuncAttributeMaxDynamicSharedMemorySize, BIG_LDS);
    hipFuncSetAttribute((const void*)&conv64_mfma<2>,
                        hipFuncAttributeMaxDynamicSharedMemorySize, BIG_LDS);
    hipFuncSetAttribute((const void*)&conv_last_mfma,
                        hipFuncAttributeMaxDynamicSharedMemorySize, BIG_LDS);
    hipFuncSetAttribute((const void*)&conv0_mfma,
                        hipFuncAttributeMaxDynamicSharedMemorySize, LDS0);

    zero_ints<<<dim3((N + 255) / 256), dim3(256), 0, stream>>>(counts, N);
    const int RT = 4 * 130 * 512;
    repack_wh<<<dim3((RT + 255) / 256), dim3(256), 0, stream>>>(cw1, fw1, Wh1);
    repack_wh<<<dim3((RT + 255) / 256), dim3(256), 0, stream>>>(cw2, fw2, Wh2);
    repack_wh3<<<dim3((130 * 512 + 255) / 256), dim3(256), 0, stream>>>(cw3, fw3, Wh3);
    repack_w0h<<<dim3((4 * 9 * 512 + 255) / 256), dim3(256), 0, stream>>>(cw0, fw0, W0h);
    edge_hist<<<dim3((E + 255) / 256), dim3(256), 0, stream>>>(ei, ej, counts, E);
    scan_kernel<<<dim3(1), dim3(1024), 0, stream>>>(counts, offs, cursor, N);
    edge_scatter<<<dim3((E + 255) / 256), dim3(256), 0, stream>>>(ei, ej, pos, cursor, csr_all, E);

    const int nb = (N + 15) / 16;
    conv0_mfma<<<dim3(nb), dim3(1024), LDS0, stream>>>(
        feat, W0h, cb0, fb0, offs, csr_all, xh0, N);
    conv64_mfma<1><<<dim3(nb), dim3(1024), BIG_LDS, stream>>>(
        xh0, (const float*)nullptr, Wh1, cb1, fb1, offs, csr_all, ansB, xhB, N);
    conv64_mfma<2><<<dim3(nb), dim3(1024), BIG_LDS, stream>>>(
        xhB, ansB, Wh2, cb2, fb2, offs, csr_all, (float*)nullptr, xhC, N);
    conv_last_mfma<<<dim3(nb), dim3(1024), BIG_LDS, stream>>>(
        xhC, Wh3, cb3, fb3, offs, csr_all, outp, N);
}

// Round 7
// 829.686 us; speedup vs baseline: 2.6538x; 1.0327x over previous
//
#include <hip/hip_runtime.h>
#include <math.h>

typedef _Float16 h8 __attribute__((ext_vector_type(8)));
typedef _Float16 h2 __attribute__((ext_vector_type(2)));
typedef float f32x4 __attribute__((ext_vector_type(4)));
typedef unsigned u32x2 __attribute__((ext_vector_type(2)));
typedef unsigned u32x4 __attribute__((ext_vector_type(4)));

__device__ __forceinline__ float clampf(float x, float lo, float hi) {
    return fminf(fmaxf(x, lo), hi);
}

__global__ void zero_ints(int* __restrict__ p, int n) {
    int i = blockIdx.x * 256 + threadIdx.x;
    if (i < n) p[i] = 0;
}

// fp16 B repack for CIN=64 layers, frag-major physical k' (= p) layout:
// p < 4096:  tile = p>>8 (mt = tile>>2, ct = tile&3); g = (p>>6)&3;
//            m = (p>>2)&15; i = p&3; bin = mt*16+g*4+i; c = ct*16+m -> cw[bin][c]
// p >= 4096: fw row c = p-4096   (4096..4159; 130 K-steps * 32 = 4160 exactly)
__global__ void repack_wh(const float* __restrict__ cw, const float* __restrict__ fw,
                          _Float16* __restrict__ Wh) {
    int idx = blockIdx.x * 256 + threadIdx.x;
    int total = 4 * 130 * 512;
    if (idx >= total) return;
    int j8 = idx & 7;
    int l = (idx >> 3) & 63;
    int rest = idx >> 9;
    int s = rest % 130;
    int t = rest / 130;
    int p = s * 32 + ((l >> 4) * 8) + j8;
    int co = t * 16 + (l & 15);
    float v = 0.f;
    if (p < 4096) {
        int tile = p >> 8;
        int g = (p >> 6) & 3;
        int m = (p >> 2) & 15;
        int i = p & 3;
        int mt = tile >> 2;
        int ct = tile & 3;
        int bin = mt * 16 + g * 4 + i;
        int c = ct * 16 + m;
        v = cw[(bin * 64 + c) * 64 + co];
    } else if (p < 4160) {
        v = fw[(p - 4096) * 64 + co];
    }
    Wh[idx] = (_Float16)v;
}

// Same p-layout, COUT=2 (layer 3).
__global__ void repack_wh3(const float* __restrict__ cw, const float* __restrict__ fw,
                           _Float16* __restrict__ Wh) {
    int idx = blockIdx.x * 256 + threadIdx.x;
    int total = 130 * 512;
    if (idx >= total) return;
    int j8 = idx & 7;
    int l = (idx >> 3) & 63;
    int s = idx >> 9;
    int p = s * 32 + ((l >> 4) * 8) + j8;
    int co = l & 15;
    float v = 0.f;
    if (co < 2) {
        if (p < 4096) {
            int tile = p >> 8;
            int g = (p >> 6) & 3;
            int m = (p >> 2) & 15;
            int i = p & 3;
            int mt = tile >> 2;
            int ct = tile & 3;
            int bin = mt * 16 + g * 4 + i;
            int c = ct * 16 + m;
            v = cw[(bin * 64 + c) * 2 + co];
        } else if (p < 4160) {
            v = fw[(p - 4096) * 2 + co];
        }
    }
    Wh[idx] = (_Float16)v;
}

// Layer-0 combined weight repack. p<256: bin = p&63, c = p>>6 (Cin=4);
// p in [256,260): dense row c' = p-256; p>=260: pad 0.
// cols co<32 = lin (fw0), co>=32 = conv (cw0).
__global__ void repack_w0h(const float* __restrict__ cw0, const float* __restrict__ fw0,
                           _Float16* __restrict__ Wh) {
    int idx = blockIdx.x * 256 + threadIdx.x;
    int total = 4 * 9 * 512;
    if (idx >= total) return;
    int j8 = idx & 7;
    int l = (idx >> 3) & 63;
    int rest = idx >> 9;
    int s = rest % 9;
    int t = rest / 9;
    int p = s * 32 + ((l >> 4) * 8) + j8;
    int co = t * 16 + (l & 15);
    float v = 0.f;
    if (p < 256) {
        int bin = p & 63;
        int c = p >> 6;
        if (co >= 32) v = cw0[(bin * 4 + c) * 32 + (co - 32)];
    } else if (p < 260) {
        int c = p - 256;
        if (co < 32) v = fw0[c * 32 + co];
    }
    Wh[idx] = (_Float16)v;
}

__global__ void edge_hist(const int* __restrict__ ei, const int* __restrict__ ej,
                          int* __restrict__ counts, int E) {
    int e = blockIdx.x * 256 + threadIdx.x;
    if (e >= E) return;
    int i = ei[e], j = ej[e];
    if (i != j) atomicAdd(&counts[i], 1);
}

__global__ __launch_bounds__(1024) void scan_kernel(const int* __restrict__ counts,
                                                    int* __restrict__ offs,
                                                    int* __restrict__ cursor, int N) {
    __shared__ int sums[1024];
    const int t = threadIdx.x;
    const int per = (N + 1023) / 1024;
    const int lo = t * per;
    const int hi = min(lo + per, N);
    int s = 0;
    for (int i = lo; i < hi; ++i) s += counts[i];
    sums[t] = s;
    __syncthreads();
    for (int d = 1; d < 1024; d <<= 1) {
        int v = (t >= d) ? sums[t - d] : 0;
        __syncthreads();
        sums[t] += v;
        __syncthreads();
    }
    int run = (t > 0) ? sums[t - 1] : 0;
    for (int i = lo; i < hi; ++i) {
        offs[i] = run;
        cursor[i] = run;
        run += counts[i];
    }
    if (t == 1023) offs[N] = sums[1023];
}

// csr_all[e] = uint4:
//   .x = j[0:17) | r0>>1 [17:19) | r1>>1 [19:21) | iv [21:24)
//   .z = fp16x2 {wu0*gv, wu0*fv}   (even u-row r0 taps at iv, iv+1)
//   .w = fp16x2 {wu1*gv, wu1*fv}   (odd  u-row r1 taps at iv, iv+1)
__global__ void edge_scatter(const int* __restrict__ ei, const int* __restrict__ ej,
                             const float* __restrict__ pos, int* __restrict__ cursor,
                             uint4* __restrict__ csr_all, int E) {
    int e = blockIdx.x * 256 + threadIdx.x;
    if (e >= E) return;
    int i = ei[e], j = ej[e];
    if (i == j) return;
    float dx = clampf(pos[i * 2 + 0] - pos[j * 2 + 0], -1.f, 1.f);
    float dy = clampf(pos[i * 2 + 1] - pos[j * 2 + 1], -1.f, 1.f);
    float r = sqrtf(dx * dx + dy * dy + 1e-12f);
    float u = clampf(2.f * r - 1.f, -1.f, 1.f);
    float v = atan2f(dy, dx) * 0.3183098861837907f;  // / pi
    float tu = (u + 1.f) * 3.5f;
    float tv = (v + 1.f) * 3.5f;
    int iu = min(6, max(0, (int)floorf(tu)));
    int iv = min(6, max(0, (int)floorf(tv)));
    float fu = clampf(tu - (float)iu, 0.f, 1.f);
    float fv = clampf(tv - (float)iv, 0.f, 1.f);
    bool even = (iu & 1) == 0;
    int rowi0 = even ? iu : iu + 1;  // even u-row
    int rowi1 = even ? iu + 1 : iu;  // odd u-row
    float wu0 = even ? (1.f - fu) : fu;
    float wu1 = even ? fu : (1.f - fu);
    float gv = 1.f - fv;
    unsigned a0 = (unsigned)__builtin_bit_cast(unsigned short, (_Float16)(wu0 * gv)) |
                  ((unsigned)__builtin_bit_cast(unsigned short, (_Float16)(wu0 * fv)) << 16);
    unsigned a1 = (unsigned)__builtin_bit_cast(unsigned short, (_Float16)(wu1 * gv)) |
                  ((unsigned)__builtin_bit_cast(unsigned short, (_Float16)(wu1 * fv)) << 16);
    int p = atomicAdd(&cursor[i], 1);
    csr_all[p] = make_uint4(
        (unsigned)j | ((unsigned)(rowi0 >> 1) << 17) | ((unsigned)(rowi1 >> 1) << 19) |
            ((unsigned)iv << 21),
        0u, a0, a1);
}

// ---------------------------------------------------------------------------
// Shared phase 1: per-wave 32-edge K-tiles.
//   A = basis [64 bins x 32 e] fp16, zeroed + 4-tap sparse scatter (r4-verified).
//   B = gathered xh rows, subtiled [sub=(e>>2)*4+(c>>4)][e&3][c&15], natural
//       row order (b128 writes).
//   B-frags via ds_read_b64_tr_b16 (chunk-gather transpose): lane supplies the
//       address of ITS OWN 8-byte chunk — addr = tile_base + m*8 (r6 bug was
//       m*2: treated the per-lane term as a column index, not a chunk addr).
//       Group q's 16 lanes span sub-tile (8q+ct)'s 128 B; lane m receives
//       column m = edges q*8+0..3 (imm ct*128) / q*8+4..7 (imm ct*128+512)
//       at channel ct*16+m — the exact MFMA B-frag.
//   Rule #18: lgkmcnt(0) + sched_barrier(0) between tr reads and MFMAs.
//   "=&v" early-clobber: 2nd tr-read consumes addr after 1st writes outputs.
__device__ __forceinline__ void mom_phase1_64(
    const _Float16* __restrict__ xh, const uint4* __restrict__ csr_all,
    _Float16* Ast, _Float16* Bst, unsigned bst_byte,
    int e0, int e1, int lane, f32x4* acc) {
    const int half = lane >> 5;
    const int el = lane & 31;
    const int q = lane >> 4;
    const int m = lane & 15;
    for (int bs = e0; bs < e1; bs += 32) {
        {  // zero A (4 KB)
            uint4 z4 = make_uint4(0, 0, 0, 0);
#pragma unroll
            for (int zz = 0; zz < 4; ++zz) ((uint4*)Ast)[zz * 64 + lane] = z4;
        }
        int e = bs + el;
        bool ok = e < e1;
        uint4 ca = csr_all[ok ? e : e0];
        int jme = ok ? (int)(ca.x & 0x1FFFF) : -1;
        {
            int iv = (ca.x >> 21) & 7;
            int rowi = half ? (int)((((ca.x >> 19) & 3) << 1) + 1)
                            : (int)(((ca.x >> 17) & 3) << 1);
            h2 wts = __builtin_bit_cast(h2, half ? ca.w : ca.z);
            if (ok) {
                int bin0 = rowi * 8 + iv;
                int bin1 = bin0 + 1;
                int a0 = bin0 * 32 + (((el >> 3) + (bin0 >> 1)) & 3) * 8 + (el & 7);
                int a1 = bin1 * 32 + (((el >> 3) + (bin1 >> 1)) & 3) * 8 + (el & 7);
                Ast[a0] = wts[0];
                Ast[a1] = wts[1];
            }
        }
        // B gather: 4 iters, each stages 8 edges x 64 ch (b128 writes)
#pragma unroll
        for (int it = 0; it < 4; ++it) {
            int ee = it * 8 + (lane >> 3);
            int jj = __shfl(jme, ee);
            int c0 = (lane & 7) * 8;
            uint4 bv = make_uint4(0, 0, 0, 0);
            if (jj >= 0) bv = *(const uint4*)(xh + (size_t)jj * 64 + c0);
            int sub = (ee >> 2) * 4 + (c0 >> 4);
            ((uint4*)Bst)[sub * 8 + (ee & 3) * 2 + ((c0 >> 3) & 1)] = bv;
        }
        // A-frags (b128, compiler-scheduled; stores above alias -> ordered)
        h8 af[4];
#pragma unroll
        for (int mt = 0; mt < 4; ++mt) {
            int binr = mt * 16 + m;
            int aoff = binr * 32 + ((q + (binr >> 1)) & 3) * 8;
            af[mt] = *(const h8*)(Ast + aoff);
        }
        // B-frags via HW transpose read (chunk addr = tile_base + m*8)
        unsigned bb = bst_byte + (unsigned)(q * 1024 + m * 8);
        h8 bf[4];
#pragma unroll
        for (int ct = 0; ct < 4; ++ct) {
            u32x2 lo, hi;
            asm volatile("ds_read_b64_tr_b16 %0, %2 offset:%3\n\t"
                         "ds_read_b64_tr_b16 %1, %2 offset:%4"
                         : "=&v"(lo), "=&v"(hi)
                         : "v"(bb), "i"(ct * 128), "i"(ct * 128 + 512)
                         : "memory");
            u32x4 t;
            t[0] = lo[0]; t[1] = lo[1]; t[2] = hi[0]; t[3] = hi[1];
            bf[ct] = __builtin_bit_cast(h8, t);
        }
        asm volatile("s_waitcnt lgkmcnt(0)" ::: "memory");
        __builtin_amdgcn_sched_barrier(0);
#pragma unroll
        for (int mt = 0; mt < 4; ++mt)
#pragma unroll
            for (int ct = 0; ct < 4; ++ct)
                acc[mt * 4 + ct] = __builtin_amdgcn_mfma_f32_16x16x32_f16(
                    af[mt], bf[ct], acc[mt * 4 + ct], 0, 0, 0);
    }
}

// Writeback acc[16] -> frag-major p-layout (p = t*256 + g*64 + m*4 + i), fp16.
__device__ __forceinline__ void mom_writeback_64(const f32x4* acc, _Float16* momrow,
                                                 int lane) {
#pragma unroll
    for (int t = 0; t < 16; ++t) {
        h2 lo = {(_Float16)acc[t][0], (_Float16)acc[t][1]};
        h2 hi = {(_Float16)acc[t][2], (_Float16)acc[t][3]};
        h2* dst = (h2*)(momrow + t * 256 + (lane >> 4) * 64 + (lane & 15) * 4);
        dst[0] = lo;
        dst[1] = hi;
    }
}

// ---------------------------------------------------------------------------
// Layers 1..2 (CIN=64, COUT=64).
// MODE 1: out32 = gemm+cb+fb (residual src), xh_out = fp16(relu(out32))
// MODE 2: res += x32 (residual); only xh_out written.
template <int MODE>
__global__ __launch_bounds__(1024, 4) void conv64_mfma(
    const _Float16* __restrict__ xh, const float* __restrict__ x32,
    const _Float16* __restrict__ Wh,
    const float* __restrict__ cb, const float* __restrict__ fb,
    const int* __restrict__ offs, const uint4* __restrict__ csr_all,
    float* __restrict__ out32, _Float16* __restrict__ xh_out, int nNodes) {
    constexpr int TM = 16;
    constexpr int KSTEPS = 130;
    constexpr int RSH = 4184;            // halfs per node row (8368 B)
    extern __shared__ _Float16 smem[];   // 16 * 4184 * 2 = 133888 B
    const int tid = threadIdx.x;
    const int w = tid >> 6;
    const int lane = tid & 63;
    const int base = blockIdx.x * TM;
    const int n = base + w;

    _Float16* Ast = smem + w * RSH;      // 2048 halfs staging (overlays mom row)
    _Float16* Bst = Ast + 2048;          // 2048 halfs
    const unsigned bst_byte = (unsigned)((w * RSH + 2048) * 2);

    f32x4 acc[16] = {{0, 0, 0, 0}, {0, 0, 0, 0}, {0, 0, 0, 0}, {0, 0, 0, 0},
                     {0, 0, 0, 0}, {0, 0, 0, 0}, {0, 0, 0, 0}, {0, 0, 0, 0},
                     {0, 0, 0, 0}, {0, 0, 0, 0}, {0, 0, 0, 0}, {0, 0, 0, 0},
                     {0, 0, 0, 0}, {0, 0, 0, 0}, {0, 0, 0, 0}, {0, 0, 0, 0}};

    if (n < nNodes) {
        mom_phase1_64(xh, csr_all, Ast, Bst, bst_byte, offs[n], offs[n + 1], lane, acc);
        mom_writeback_64(acc, smem + w * RSH, lane);
        smem[w * RSH + 4096 + lane] = xh[(size_t)n * 64 + lane];  // dense row
    }

    // ---- phase 2: K-chunk for this wave (130 = 2*9 + 14*8)
    const int s0 = w * 8 + min(w, 2);
    const int s_end = s0 + 8 + (w < 2 ? 1 : 0);
    const int quad = lane >> 4;
    const _Float16* arow = smem + (lane & 15) * RSH;

    const uint4* Bp = (const uint4*)Wh;
    uint4 b0[4], b1[4];
#pragma unroll
    for (int t = 0; t < 4; ++t) {  // global prefetch (no LDS dep) before barrier
        b0[t] = Bp[((size_t)t * KSTEPS + s0) * 64 + lane];
        b1[t] = Bp[((size_t)t * KSTEPS + s0 + 1) * 64 + lane];
    }
    __syncthreads();
    f32x4 acc2[4] = {{0, 0, 0, 0}, {0, 0, 0, 0}, {0, 0, 0, 0}, {0, 0, 0, 0}};
    for (int s = s0; s < s_end; ++s) {
        uint4 bq[4];
#pragma unroll
        for (int t = 0; t < 4; ++t) {
            bq[t] = b0[t];
            b0[t] = b1[t];
            if (s + 2 < s_end) b1[t] = Bp[((size_t)t * KSTEPS + s + 2) * 64 + lane];
        }
        h8 a = *(const h8*)(arow + s * 32 + quad * 8);
#pragma unroll
        for (int t = 0; t < 4; ++t)
            acc2[t] = __builtin_amdgcn_mfma_f32_16x16x32_f16(a, __builtin_bit_cast(h8, bq[t]),
                                                             acc2[t], 0, 0, 0);
    }
    __syncthreads();  // moments dead -> reuse as reduce scratch (64 KB)
    f32x4* red = (f32x4*)smem;
#pragma unroll
    for (int t = 0; t < 4; ++t) red[(w * 4 + t) * 64 + lane] = acc2[t];
    __syncthreads();
    if (w < 4) {
        f32x4 s = {0, 0, 0, 0};
#pragma unroll
        for (int g = 0; g < 16; ++g) s += red[(g * 4 + w) * 64 + lane];
        const int co = w * 16 + (lane & 15);
#pragma unroll
        for (int i = 0; i < 4; ++i) {
            int nn = base + quad * 4 + i;
            if (nn < nNodes) {
                float res = s[i] + cb[co] + fb[co];
                if (MODE == 2) res += x32[(size_t)nn * 64 + co];
                if (MODE == 1) out32[(size_t)nn * 64 + co] = res;
                xh_out[(size_t)nn * 64 + co] = (_Float16)fmaxf(res, 0.f);
            }
        }
    }
}

// ---------------------------------------------------------------------------
// Layer 3 (CIN=64, COUT=2): same phase 1 as conv64; phase 2 = 1 MFMA t-tile
// (cols 0..1 real). out = (gemm + cb3 + fb3) / 128.
__global__ __launch_bounds__(1024, 4) void conv_last_mfma(
    const _Float16* __restrict__ xh, const _Float16* __restrict__ Wh3,
    const float* __restrict__ cb3, const float* __restrict__ fb3,
    const int* __restrict__ offs, const uint4* __restrict__ csr_all,
    float* __restrict__ out, int nNodes) {
    constexpr int TM = 16;
    constexpr int RSH = 4184;
    extern __shared__ _Float16 smem[];   // 133888 B
    const int tid = threadIdx.x;
    const int w = tid >> 6;
    const int lane = tid & 63;
    const int base = blockIdx.x * TM;
    const int n = base + w;

    _Float16* Ast = smem + w * RSH;
    _Float16* Bst = Ast + 2048;
    const unsigned bst_byte = (unsigned)((w * RSH + 2048) * 2);

    f32x4 acc[16] = {{0, 0, 0, 0}, {0, 0, 0, 0}, {0, 0, 0, 0}, {0, 0, 0, 0},
                     {0, 0, 0, 0}, {0, 0, 0, 0}, {0, 0, 0, 0}, {0, 0, 0, 0},
                     {0, 0, 0, 0}, {0, 0, 0, 0}, {0, 0, 0, 0}, {0, 0, 0, 0},
                     {0, 0, 0, 0}, {0, 0, 0, 0}, {0, 0, 0, 0}, {0, 0, 0, 0}};

    if (n < nNodes) {
        mom_phase1_64(xh, csr_all, Ast, Bst, bst_byte, offs[n], offs[n + 1], lane, acc);
        mom_writeback_64(acc, smem + w * RSH, lane);
        smem[w * RSH + 4096 + lane] = xh[(size_t)n * 64 + lane];  // dense (relu'd)
    }

    const int s0 = w * 8 + min(w, 2);
    const int s_end = s0 + 8 + (w < 2 ? 1 : 0);
    const int quad = lane >> 4;
    const _Float16* arow = smem + (lane & 15) * RSH;
    const uint4* Bp = (const uint4*)Wh3;

    __syncthreads();
    f32x4 acc2 = {0, 0, 0, 0};
    for (int s = s0; s < s_end; ++s) {
        uint4 bq = Bp[(size_t)s * 64 + lane];
        h8 a = *(const h8*)(arow + s * 32 + quad * 8);
        acc2 = __builtin_amdgcn_mfma_f32_16x16x32_f16(a, __builtin_bit_cast(h8, bq),
                                                      acc2, 0, 0, 0);
    }
    __syncthreads();
    f32x4* red = (f32x4*)smem;
    red[w * 64 + lane] = acc2;
    __syncthreads();
    if (w == 0) {
        f32x4 s = {0, 0, 0, 0};
#pragma unroll
        for (int g = 0; g < 16; ++g) s += red[g * 64 + lane];
        const int co = lane & 15;
        if (co < 2) {
#pragma unroll
            for (int i = 0; i < 4; ++i) {
                int nn = base + quad * 4 + i;
                if (nn < nNodes)
                    out[nn * 2 + co] = (s[i] + cb3[co] + fb3[co]) * (1.f / 128.f);
            }
        }
    }
}

// ---------------------------------------------------------------------------
// Layer 0 (CIN=4, raw f32 x, no relu): shrunk moment-GEMM.
// B tile [8 subtiles][4 e][16 c] (c 0..3 real); tr-read chunk addr
// q*256 + m*8, imm 0/128 (subs 2q, 2q+1) -> the B-frag; 4 MFMA per tile.
__global__ __launch_bounds__(1024, 4) void conv0_mfma(
    const float* __restrict__ xf, const _Float16* __restrict__ W0h,
    const float* __restrict__ cb0, const float* __restrict__ fb0,
    const int* __restrict__ offs, const uint4* __restrict__ csr_all,
    _Float16* __restrict__ xh_out, int nNodes) {
    constexpr int TM = 16;
    constexpr int RSH0 = 296;
    constexpr int MOMSZ = 16 * RSH0;     // 4736 halfs
    extern __shared__ _Float16 smem[];   // (4736 + 16*2560)*2 = 91392 B
    const int tid = threadIdx.x;
    const int w = tid >> 6;
    const int lane = tid & 63;
    const int base = blockIdx.x * TM;
    const int n = base + w;

    _Float16* Ast = smem + MOMSZ + w * 2560;
    _Float16* Bst = Ast + 2048;
    _Float16* momrow = smem + w * RSH0;
    const unsigned bst_byte = (unsigned)((MOMSZ + w * 2560 + 2048) * 2);

    f32x4 acc[4] = {{0, 0, 0, 0}, {0, 0, 0, 0}, {0, 0, 0, 0}, {0, 0, 0, 0}};

    if (n < nNodes) {
        const int e0 = offs[n], e1 = offs[n + 1];
        const int half = lane >> 5;
        const int el = lane & 31;
        const int q = lane >> 4;
        const int m = lane & 15;
        for (int bs = e0; bs < e1; bs += 32) {
            {  // zero A
                uint4 z4 = make_uint4(0, 0, 0, 0);
#pragma unroll
                for (int zz = 0; zz < 4; ++zz) ((uint4*)Ast)[zz * 64 + lane] = z4;
            }
            int e = bs + el;
            bool ok = e < e1;
            uint4 ca = csr_all[ok ? e : e0];
            int jme = ok ? (int)(ca.x & 0x1FFFF) : -1;
            {
                int iv = (ca.x >> 21) & 7;
                int rowi = half ? (int)((((ca.x >> 19) & 3) << 1) + 1)
                                : (int)(((ca.x >> 17) & 3) << 1);
                h2 wts = __builtin_bit_cast(h2, half ? ca.w : ca.z);
                if (ok) {
                    int bin0 = rowi * 8 + iv;
                    int bin1 = bin0 + 1;
                    int a0 = bin0 * 32 + (((el >> 3) + (bin0 >> 1)) & 3) * 8 + (el & 7);
                    int a1 = bin1 * 32 + (((el >> 3) + (bin1 >> 1)) & 3) * 8 + (el & 7);
                    Ast[a0] = wts[0];
                    Ast[a1] = wts[1];
                }
            }
            // B: one edge per half-0 lane; 4 real cols + 12 zeros.
            if (half == 0) {
                float4 xj = make_float4(0.f, 0.f, 0.f, 0.f);
                if (jme >= 0) xj = *(const float4*)(xf + (size_t)jme * 4);
                h2 d0 = {(_Float16)xj.x, (_Float16)xj.y};
                h2 d1 = {(_Float16)xj.z, (_Float16)xj.w};
                uint4 bv = make_uint4(__builtin_bit_cast(unsigned, d0),
                                      __builtin_bit_cast(unsigned, d1), 0u, 0u);
                uint4* dst = (uint4*)Bst + (el >> 2) * 8 + (el & 3) * 2;
                dst[0] = bv;
                dst[1] = make_uint4(0, 0, 0, 0);
            }
            // A-frags
            h8 af[4];
#pragma unroll
            for (int mt = 0; mt < 4; ++mt) {
                int binr = mt * 16 + m;
                int aoff = binr * 32 + ((q + (binr >> 1)) & 3) * 8;
                af[mt] = *(const h8*)(Ast + aoff);
            }
            // B-frag via tr-read: chunk addr q*256 + m*8; subs 2q / 2q+1
            unsigned bb = bst_byte + (unsigned)(q * 256 + m * 8);
            u32x2 lo, hi;
            asm volatile("ds_read_b64_tr_b16 %0, %2 offset:0\n\t"
                         "ds_read_b64_tr_b16 %1, %2 offset:128"
                         : "=&v"(lo), "=&v"(hi)
                         : "v"(bb)
                         : "memory");
            u32x4 tt;
            tt[0] = lo[0]; tt[1] = lo[1]; tt[2] = hi[0]; tt[3] = hi[1];
            h8 b = __builtin_bit_cast(h8, tt);
            asm volatile("s_waitcnt lgkmcnt(0)" ::: "memory");
            __builtin_amdgcn_sched_barrier(0);
#pragma unroll
            for (int mt = 0; mt < 4; ++mt)
                acc[mt] = __builtin_amdgcn_mfma_f32_16x16x32_f16(af[mt], b, acc[mt], 0, 0, 0);
        }
        // writeback: p = bin + 64*c, only c = lane&15 < 4 valid
        if ((lane & 15) < 4) {
#pragma unroll
            for (int mt = 0; mt < 4; ++mt) {
                _Float16* dst = momrow + mt * 16 + (lane >> 4) * 4 + 64 * (lane & 15);
                ((h2*)dst)[0] = h2{(_Float16)acc[mt][0], (_Float16)acc[mt][1]};
                ((h2*)dst)[1] = h2{(_Float16)acc[mt][2], (_Float16)acc[mt][3]};
            }
        }
        if (lane < 7) {  // zero pad p in [260, 288)
            h2 z = {(_Float16)0.f, (_Float16)0.f};
            h2* zp = (h2*)(momrow + 260 + lane * 4);
            zp[0] = z;
            zp[1] = z;
        }
        if (lane < 4) momrow[256 + lane] = (_Float16)xf[(size_t)n * 4 + lane];  // dense raw
    }

    // phase 2: 9 K-steps over 16 waves (waves 9..15 idle)
    const int quad = lane >> 4;
    const _Float16* arow = smem + (lane & 15) * RSH0;
    const uint4* Bp = (const uint4*)W0h;
    __syncthreads();
    f32x4 acc2[4] = {{0, 0, 0, 0}, {0, 0, 0, 0}, {0, 0, 0, 0}, {0, 0, 0, 0}};
    const int s0 = min(w, 9), s_end = min(w + 1, 9);
    for (int s = s0; s < s_end; ++s) {
        uint4 bq[4];
#pragma unroll
        for (int t = 0; t < 4; ++t) bq[t] = Bp[((size_t)t * 9 + s) * 64 + lane];
        h8 a = *(const h8*)(arow + s * 32 + quad * 8);
#pragma unroll
        for (int t = 0; t < 4; ++t)
            acc2[t] = __builtin_amdgcn_mfma_f32_16x16x32_f16(a, __builtin_bit_cast(h8, bq[t]),
                                                             acc2[t], 0, 0, 0);
    }
    __syncthreads();
    f32x4* red = (f32x4*)(smem + MOMSZ);  // overlays dead staging
#pragma unroll
    for (int t = 0; t < 4; ++t) red[(w * 4 + t) * 64 + lane] = acc2[t];
    __syncthreads();
    if (w < 4) {
        f32x4 s = {0, 0, 0, 0};
#pragma unroll
        for (int g = 0; g < 16; ++g) s += red[(g * 4 + w) * 64 + lane];
        const int co = w * 16 + (lane & 15);
        const float bias = (co < 32) ? fb0[co] : cb0[co - 32];
#pragma unroll
        for (int i = 0; i < 4; ++i) {
            int nn = base + quad * 4 + i;
            if (nn < nNodes)
                xh_out[(size_t)nn * 64 + co] = (_Float16)fmaxf(s[i] + bias, 0.f);
        }
    }
}

extern "C" void kernel_launch(void* const* d_in, const int* in_sizes, int n_in,
                              void* d_out, int out_size, void* d_ws, size_t ws_size,
                              hipStream_t stream) {
    const float* pos = (const float*)d_in[0];
    const float* feat = (const float*)d_in[1];
    const int* ei = (const int*)d_in[2];
    const int* ej = (const int*)d_in[3];
    const float* cw0 = (const float*)d_in[4];
    const float* cb0 = (const float*)d_in[5];
    const float* fw0 = (const float*)d_in[6];
    const float* fb0 = (const float*)d_in[7];
    const float* cw1 = (const float*)d_in[8];
    const float* cb1 = (const float*)d_in[9];
    const float* fw1 = (const float*)d_in[10];
    const float* fb1 = (const float*)d_in[11];
    const float* cw2 = (const float*)d_in[12];
    const float* cb2 = (const float*)d_in[13];
    const float* fw2 = (const float*)d_in[14];
    const float* fb2 = (const float*)d_in[15];
    const float* cw3 = (const float*)d_in[16];
    const float* cb3 = (const float*)d_in[17];
    const float* fw3 = (const float*)d_in[18];
    const float* fb3 = (const float*)d_in[19];
    float* outp = (float*)d_out;

    const int N = in_sizes[0] / 2;
    const int E = in_sizes[2];

    char* wsp = (char*)d_ws;
    size_t off = 0;
    auto alloc = [&](size_t bytes) -> void* {
        void* p = wsp + off;
        off = (off + bytes + 255) & ~(size_t)255;
        return p;
    };
    int* counts = (int*)alloc((size_t)N * 4);
    int* offs = (int*)alloc((size_t)(N + 1) * 4);
    int* cursor = (int*)alloc((size_t)N * 4);
    uint4* csr_all = (uint4*)alloc((size_t)E * 16);
    float* ansB = (float*)alloc((size_t)N * 64 * 4);       // layer-1 f32 (residual)
    _Float16* xh0 = (_Float16*)alloc((size_t)N * 64 * 2);  // conv0 out (relu fp16)
    _Float16* xhB = (_Float16*)alloc((size_t)N * 64 * 2);  // layer-1 relu fp16
    _Float16* xhC = (_Float16*)alloc((size_t)N * 64 * 2);  // layer-2 relu fp16
    _Float16* Wh1 = (_Float16*)alloc((size_t)4 * 130 * 512 * 2);
    _Float16* Wh2 = (_Float16*)alloc((size_t)4 * 130 * 512 * 2);
    _Float16* Wh3 = (_Float16*)alloc((size_t)130 * 512 * 2);
    _Float16* W0h = (_Float16*)alloc((size_t)4 * 9 * 512 * 2);
    (void)ws_size;
    (void)n_in;
    (void)out_size;

    const int BIG_LDS = 16 * 4184 * 2;             // 133888 B
    const int LDS0 = (16 * 296 + 16 * 2560) * 2;   // 91392 B
    hipFuncSetAttribute((const void*)&conv64_mfma<1>,
                        hipFuncAttributeMaxDynamicSharedMemorySize, BIG_LDS);
    hipFuncSetAttribute((const void*)&conv64_mfma<2>,
                        hipFuncAttributeMaxDynamicSharedMemorySize, BIG_LDS);
    hipFuncSetAttribute((const void*)&conv_last_mfma,
                        hipFuncAttributeMaxDynamicSharedMemorySize, BIG_LDS);
    hipFuncSetAttribute((const void*)&conv0_mfma,
                        hipFuncAttributeMaxDynamicSharedMemorySize, LDS0);

    zero_ints<<<dim3((N + 255) / 256), dim3(256), 0, stream>>>(counts, N);
    const int RT = 4 * 130 * 512;
    repack_wh<<<dim3((RT + 255) / 256), dim3(256), 0, stream>>>(cw1, fw1, Wh1);
    repack_wh<<<dim3((RT + 255) / 256), dim3(256), 0, stream>>>(cw2, fw2, Wh2);
    repack_wh3<<<dim3((130 * 512 + 255) / 256), dim3(256), 0, stream>>>(cw3, fw3, Wh3);
    repack_w0h<<<dim3((4 * 9 * 512 + 255) / 256), dim3(256), 0, stream>>>(cw0, fw0, W0h);
    edge_hist<<<dim3((E + 255) / 256), dim3(256), 0, stream>>>(ei, ej, counts, E);
    scan_kernel<<<dim3(1), dim3(1024), 0, stream>>>(counts, offs, cursor, N);
    edge_scatter<<<dim3((E + 255) / 256), dim3(256), 0, stream>>>(ei, ej, pos, cursor, csr_all, E);

    const int nb = (N + 15) / 16;
    conv0_mfma<<<dim3(nb), dim3(1024), LDS0, stream>>>(
        feat, W0h, cb0, fb0, offs, csr_all, xh0, N);
    conv64_mfma<1><<<dim3(nb), dim3(1024), BIG_LDS, stream>>>(
        xh0, (const float*)nullptr, Wh1, cb1, fb1, offs, csr_all, ansB, xhB, N);
    conv64_mfma<2><<<dim3(nb), dim3(1024), BIG_LDS, stream>>>(
        xhB, ansB, Wh2, cb2, fb2, offs, csr_all, (float*)nullptr, xhC, N);
    conv_last_mfma<<<dim3(nb), dim3(1024), BIG_LDS, stream>>>(
        xhC, Wh3, cb3, fb3, offs, csr_all, outp, N);
}